// Round 1
// baseline (276.213 us; speedup 1.0000x reference)
//
#include <hip/hip_runtime.h>
#include <cstdint>

#define NB 4
#define NQ 8192
#define NC 256
#define IH 128
#define IW 128
#define NHW (IH * IW)
#define NHEADS 8
#define NP 4
#define NHD 32

__device__ __forceinline__ unsigned short f2bf(float f) {
    unsigned int u = __float_as_uint(f);
    unsigned int r = (u + 0x7FFFu + ((u >> 16) & 1u)) >> 16;
    return (unsigned short)r;
}
__device__ __forceinline__ float bf2f(unsigned short s) {
    return __uint_as_float(((unsigned int)s) << 16);
}
__device__ __forceinline__ void fma4(float4& acc, float s, const float4& w) {
    acc.x = fmaf(s, w.x, acc.x);
    acc.y = fmaf(s, w.y, acc.y);
    acc.z = fmaf(s, w.z, acc.z);
    acc.w = fmaf(s, w.w, acc.w);
}

// ---------------------------------------------------------------------------
// K1: vproj[b,pix,c] = value[b,pix,:] @ W_v + b_v   (stored as bf16)
// block: 256 threads, 32 rows per block. wave w handles rows 8w..8w+7,
// each lane owns 4 consecutive cols (c0 = (t&63)*4) -> wave covers all 256.
// ---------------------------------------------------------------------------
__global__ __launch_bounds__(256) void k_vproj(
    const float* __restrict__ value, const float* __restrict__ Wv,
    const float* __restrict__ bv, unsigned short* __restrict__ vproj)
{
    const int t = threadIdx.x;
    const int wave = t >> 6;
    const int c0 = (t & 63) * 4;
    const size_t row0 = (size_t)blockIdx.x * 32;

    __shared__ float val[32][NC];
    {
        const float4* src = reinterpret_cast<const float4*>(value + row0 * NC);
        float4* dst = reinterpret_cast<float4*>(&val[0][0]);
#pragma unroll
        for (int i = 0; i < 8; ++i) dst[i * 256 + t] = src[i * 256 + t];
    }
    __syncthreads();

    float4 acc[8];
#pragma unroll
    for (int r = 0; r < 8; ++r) acc[r] = make_float4(0.f, 0.f, 0.f, 0.f);

    for (int k4 = 0; k4 < 64; ++k4) {
        const float4 w0 = *reinterpret_cast<const float4*>(&Wv[(size_t)(k4 * 4 + 0) * NC + c0]);
        const float4 w1 = *reinterpret_cast<const float4*>(&Wv[(size_t)(k4 * 4 + 1) * NC + c0]);
        const float4 w2 = *reinterpret_cast<const float4*>(&Wv[(size_t)(k4 * 4 + 2) * NC + c0]);
        const float4 w3 = *reinterpret_cast<const float4*>(&Wv[(size_t)(k4 * 4 + 3) * NC + c0]);
#pragma unroll
        for (int r = 0; r < 8; ++r) {
            const float4 a = *reinterpret_cast<const float4*>(&val[wave * 8 + r][k4 * 4]);
            fma4(acc[r], a.x, w0);
            fma4(acc[r], a.y, w1);
            fma4(acc[r], a.z, w2);
            fma4(acc[r], a.w, w3);
        }
    }

    const float4 bvv = *reinterpret_cast<const float4*>(&bv[c0]);
#pragma unroll
    for (int r = 0; r < 8; ++r) {
        ushort4 pk;
        pk.x = f2bf(acc[r].x + bvv.x);
        pk.y = f2bf(acc[r].y + bvv.y);
        pk.z = f2bf(acc[r].z + bvv.z);
        pk.w = f2bf(acc[r].w + bvv.w);
        *reinterpret_cast<ushort4*>(&vproj[(row0 + wave * 8 + r) * NC + c0]) = pk;
    }
}

// ---------------------------------------------------------------------------
// K2: per query: offsets = q@W_off+b_off, attn = softmax(q@W_attn+b_attn, P),
//     locs = clip(ref + off*0.1/dim, 0, 1). 16 queries/block, 128 threads.
//     thread t<64 -> offset col t; 64<=t<96 -> attn col t-64; t>=96 idle-ish.
// ---------------------------------------------------------------------------
__global__ __launch_bounds__(128) void k_offattn(
    const float* __restrict__ query, const float* __restrict__ refp,
    const float* __restrict__ Woff, const float* __restrict__ boff,
    const float* __restrict__ Wattn, const float* __restrict__ battn,
    float* __restrict__ locs, float* __restrict__ attnw)
{
    const int t = threadIdx.x;
    const size_t q0 = (size_t)blockIdx.x * 16;

    __shared__ float qrow[16][NC];
    __shared__ float refs[16][2];
    {
        const float4* src = reinterpret_cast<const float4*>(query + q0 * NC);
        float4* dst = reinterpret_cast<float4*>(&qrow[0][0]);
#pragma unroll
        for (int i = 0; i < 8; ++i) dst[i * 128 + t] = src[i * 128 + t];
        if (t < 32) reinterpret_cast<float*>(refs)[t] = refp[q0 * 2 + t];
    }
    __syncthreads();

    const int c = t;
    const float* wp;
    int wstride;
    if (c < 64) { wp = Woff + c; wstride = 64; }
    else        { wp = Wattn + (c & 31); wstride = 32; }

    float acc[16];
#pragma unroll
    for (int r = 0; r < 16; ++r) acc[r] = 0.f;

    for (int k4 = 0; k4 < 64; ++k4) {
        float w0 = wp[(size_t)(k4 * 4 + 0) * wstride];
        float w1 = wp[(size_t)(k4 * 4 + 1) * wstride];
        float w2 = wp[(size_t)(k4 * 4 + 2) * wstride];
        float w3 = wp[(size_t)(k4 * 4 + 3) * wstride];
#pragma unroll
        for (int r = 0; r < 16; ++r) {
            const float4 a = *reinterpret_cast<const float4*>(&qrow[r][k4 * 4]);
            acc[r] = fmaf(a.x, w0, acc[r]);
            acc[r] = fmaf(a.y, w1, acc[r]);
            acc[r] = fmaf(a.z, w2, acc[r]);
            acc[r] = fmaf(a.w, w3, acc[r]);
        }
    }

    if (c < 64) {
        const float bias = boff[c];
        const int xy = c & 1;
#pragma unroll
        for (int r = 0; r < 16; ++r) {
            float off = acc[r] + bias;
            float loc = refs[r][xy] + off * (0.1f / 128.0f);
            loc = fminf(fmaxf(loc, 0.f), 1.f);
            locs[(q0 + r) * 64 + c] = loc;
        }
    } else if (c < 96) {
        const int l = c - 64;
        const float bias = battn[l];
#pragma unroll
        for (int r = 0; r < 16; ++r) {
            float v = acc[r] + bias;
            float m = fmaxf(v, __shfl_xor(v, 1));
            m = fmaxf(m, __shfl_xor(m, 2));
            float e = __expf(v - m);
            float s = e + __shfl_xor(e, 1);
            s = s + __shfl_xor(s, 2);
            attnw[(q0 + r) * 32 + l] = e / s;
        }
    }
}

// ---------------------------------------------------------------------------
// K3: bilinear gather + point aggregation + output projection.
// 16 queries/block, 256 threads; thread t -> (h = t>>5, dd = t&31) = agg col t.
// ---------------------------------------------------------------------------
__global__ __launch_bounds__(256) void k_sample(
    const unsigned short* __restrict__ vproj, const float* __restrict__ locs,
    const float* __restrict__ attnw, const float* __restrict__ Wout,
    const float* __restrict__ bout, float* __restrict__ out)
{
    const int t = threadIdx.x;
    const size_t q0 = (size_t)blockIdx.x * 16;
    const int b = (int)(q0 / NQ);
    const int h = t >> 5;

    __shared__ float locs_s[16][64];
    __shared__ float attn_s[16][32];
    __shared__ float agg_s[16][NC];

    {
        const float4* ls = reinterpret_cast<const float4*>(locs + q0 * 64);
        float4* ld = reinterpret_cast<float4*>(&locs_s[0][0]);
        ld[t] = ls[t];  // 256 float4 = 1024 floats
        const float2* as = reinterpret_cast<const float2*>(attnw + q0 * 32);
        float2* ad = reinterpret_cast<float2*>(&attn_s[0][0]);
        ad[t] = as[t];  // 256 float2 = 512 floats
    }
    __syncthreads();

    const unsigned short* __restrict__ vb =
        vproj + (size_t)b * NHW * NC + (h * NHD + (t & 31));

#pragma unroll 1
    for (int r = 0; r < 16; ++r) {
        float a = 0.f;
#pragma unroll
        for (int p = 0; p < 4; ++p) {
            const float lx = locs_s[r][h * 8 + p * 2 + 0];
            const float ly = locs_s[r][h * 8 + p * 2 + 1];
            const float aw = attn_s[r][h * 4 + p];
            const float x = lx * (float)IW - 0.5f;
            const float y = ly * (float)IH - 0.5f;
            const float x0f = floorf(x), y0f = floorf(y);
            const float wx = x - x0f, wy = y - y0f;
            const int ix0 = (int)x0f, iy0 = (int)y0f;
            const int ix1 = ix0 + 1, iy1 = iy0 + 1;
            const int cx0 = max(ix0, 0), cy0 = max(iy0, 0);
            const int cx1 = min(ix1, IW - 1), cy1 = min(iy1, IH - 1);
            const float vx0 = (ix0 >= 0) ? 1.f : 0.f;
            const float vy0 = (iy0 >= 0) ? 1.f : 0.f;
            const float vx1 = (ix1 < IW) ? 1.f : 0.f;
            const float vy1 = (iy1 < IH) ? 1.f : 0.f;
            const float f00 = bf2f(vb[(size_t)(cy0 * IW + cx0) * NC]);
            const float f01 = bf2f(vb[(size_t)(cy0 * IW + cx1) * NC]);
            const float f10 = bf2f(vb[(size_t)(cy1 * IW + cx0) * NC]);
            const float f11 = bf2f(vb[(size_t)(cy1 * IW + cx1) * NC]);
            const float s = f00 * ((1.f - wx) * (1.f - wy) * vx0 * vy0)
                          + f01 * (wx * (1.f - wy) * vx1 * vy0)
                          + f10 * ((1.f - wx) * wy * vx0 * vy1)
                          + f11 * (wx * wy * vx1 * vy1);
            a = fmaf(aw, s, a);
        }
        agg_s[r][t] = a;
    }
    __syncthreads();

    float acc[16];
    const float bb = bout[t];
#pragma unroll
    for (int r = 0; r < 16; ++r) acc[r] = bb;

    for (int k4 = 0; k4 < 64; ++k4) {
        const float w0 = Wout[(size_t)(k4 * 4 + 0) * NC + t];
        const float w1 = Wout[(size_t)(k4 * 4 + 1) * NC + t];
        const float w2 = Wout[(size_t)(k4 * 4 + 2) * NC + t];
        const float w3 = Wout[(size_t)(k4 * 4 + 3) * NC + t];
#pragma unroll
        for (int r = 0; r < 16; ++r) {
            const float4 a = *reinterpret_cast<const float4*>(&agg_s[r][k4 * 4]);
            acc[r] = fmaf(a.x, w0, acc[r]);
            acc[r] = fmaf(a.y, w1, acc[r]);
            acc[r] = fmaf(a.z, w2, acc[r]);
            acc[r] = fmaf(a.w, w3, acc[r]);
        }
    }

#pragma unroll
    for (int r = 0; r < 16; ++r)
        out[(q0 + r) * NC + t] = acc[r];
}

extern "C" void kernel_launch(void* const* d_in, const int* in_sizes, int n_in,
                              void* d_out, int out_size, void* d_ws, size_t ws_size,
                              hipStream_t stream) {
    const float* query = (const float*)d_in[0];
    const float* refp  = (const float*)d_in[1];
    const float* value = (const float*)d_in[2];
    const float* Woff  = (const float*)d_in[3];
    const float* boff  = (const float*)d_in[4];
    const float* Wattn = (const float*)d_in[5];
    const float* battn = (const float*)d_in[6];
    const float* Wv    = (const float*)d_in[7];
    const float* bv    = (const float*)d_in[8];
    const float* Wout  = (const float*)d_in[9];
    const float* bout  = (const float*)d_in[10];
    float* out = (float*)d_out;

    // workspace layout
    unsigned short* vproj = (unsigned short*)d_ws;                  // 16,777,216 bf16 = 32 MB
    float* locs  = (float*)(vproj + (size_t)NB * NHW * NC);         //  2,097,152 f32 =  8 MB
    float* attnw = locs + (size_t)NB * NQ * NHEADS * NP * 2;        //  1,048,576 f32 =  4 MB

    k_vproj<<<dim3(NB * NHW / 32), dim3(256), 0, stream>>>(value, Wv, bv, vproj);
    k_offattn<<<dim3(NB * NQ / 16), dim3(128), 0, stream>>>(query, refp, Woff, boff,
                                                            Wattn, battn, locs, attnw);
    k_sample<<<dim3(NB * NQ / 16), dim3(256), 0, stream>>>(vproj, locs, attnw, Wout, bout, out);
}

// Round 2
// 135.917 us; speedup vs baseline: 2.0322x; 2.0322x over previous
//
#include <hip/hip_runtime.h>
#include <cstdint>

#define NB 4
#define NQ 8192
#define NC 256
#define IH 128
#define IW 128
#define NHW (IH * IW)
#define NHEADS 8
#define NP 4
#define NHD 32

typedef __bf16 bf16x8 __attribute__((ext_vector_type(8)));
typedef float f32x4 __attribute__((ext_vector_type(4)));

union FragCast { uint4 q; bf16x8 v; };

__device__ __forceinline__ unsigned int f2bf(float f) {
    unsigned int u = __float_as_uint(f);
    return (u + 0x7FFFu + ((u >> 16) & 1u)) >> 16;
}
__device__ __forceinline__ float bf2f(unsigned short s) {
    return __uint_as_float(((unsigned int)s) << 16);
}

// ---------------------------------------------------------------------------
// k_pack: repack W (f32 [256 k][256 col] row-major) into bf16 MFMA B-fragment
// order: pk[(kt*256 + col)*32 + j] = bf16(W[(kt*32+j)*256 + col]).
// Lane of col-tile ct, chunk (l>>4) then reads 16B contiguous.
// ---------------------------------------------------------------------------
__global__ __launch_bounds__(256) void k_pack(
    const float* __restrict__ Wv, const float* __restrict__ Wout,
    unsigned short* __restrict__ pkv, unsigned short* __restrict__ pko)
{
    const int tid = blockIdx.x * 256 + threadIdx.x;   // 0..4095
    const float* src = (tid & 2048) ? Wout : Wv;
    unsigned short* dst = (tid & 2048) ? pko : pkv;
    const int rem = tid & 2047;
    const int kt = rem >> 8, col = rem & 255;
    unsigned short* d = dst + (size_t)(kt * 256 + col) * 32;
    const float* s = src + (size_t)kt * 32 * 256 + col;
#pragma unroll
    for (int j = 0; j < 32; ++j)
        d[j] = (unsigned short)f2bf(s[(size_t)j * 256]);
}

// ---------------------------------------------------------------------------
// k_vproj (MFMA): vproj[b,pix,:] = bf16(value[b,pix,:] @ Wv + bv)
// block 256 thr / 4 waves; 32 rows x 256 cols per block, K=256.
// A staged in LDS bf16, XOR-swizzled (byte ^= (row&7)<<4).
// wave w: row-tile rt=w&1, col-tiles (w>>1)*8 .. +7.  8 kt x 8 ct = 64 MFMA.
// ---------------------------------------------------------------------------
__global__ __launch_bounds__(256) void k_vproj(
    const float* __restrict__ value, const unsigned short* __restrict__ Bpk,
    const float* __restrict__ bv, unsigned short* __restrict__ vproj)
{
    const int t = threadIdx.x;
    const int l = t & 63, w = t >> 6;
    const size_t row0 = (size_t)blockIdx.x * 32;

    __shared__ unsigned short A[32 * 256];  // 16 KB, swizzled bf16

    // stage 32x256 f32 -> bf16 LDS. 2048 4-elem chunks, 8 per thread.
#pragma unroll
    for (int i = 0; i < 8; ++i) {
        const int chunk = i * 256 + t;
        const int row = chunk >> 6;
        const int k0 = (chunk & 63) * 4;
        const float4 v4 = *reinterpret_cast<const float4*>(&value[(row0 + row) * NC + k0]);
        const unsigned int lo = f2bf(v4.x) | (f2bf(v4.y) << 16);
        const unsigned int hi = f2bf(v4.z) | (f2bf(v4.w) << 16);
        unsigned int byte = (unsigned int)(row * 512 + k0 * 2);
        byte ^= (unsigned int)((row & 7) << 4);
        *reinterpret_cast<uint2*>(reinterpret_cast<char*>(A) + byte) = make_uint2(lo, hi);
    }
    __syncthreads();

    const int rt = w & 1, cg = w >> 1;
    const int arow = rt * 16 + (l & 15);
    const int achunk = l >> 4;

    f32x4 acc[8];
#pragma unroll
    for (int i = 0; i < 8; ++i) acc[i] = (f32x4)(0.f);

#pragma unroll
    for (int kt = 0; kt < 8; ++kt) {
        unsigned int abyte = (unsigned int)(arow * 512 + (kt * 32 + achunk * 8) * 2);
        abyte ^= (unsigned int)((arow & 7) << 4);
        FragCast af;
        af.q = *reinterpret_cast<const uint4*>(reinterpret_cast<const char*>(A) + abyte);
        const unsigned short* bbase = Bpk + (size_t)kt * 8192 + (l & 15) * 32 + achunk * 8;
#pragma unroll
        for (int i = 0; i < 8; ++i) {
            const int ct = cg * 8 + i;
            FragCast bf;
            bf.q = *reinterpret_cast<const uint4*>(bbase + ct * 512);
            acc[i] = __builtin_amdgcn_mfma_f32_16x16x32_bf16(af.v, bf.v, acc[i], 0, 0, 0);
        }
    }

#pragma unroll
    for (int i = 0; i < 8; ++i) {
        const int col = (cg * 8 + i) * 16 + (l & 15);
        const float bb = bv[col];
#pragma unroll
        for (int j = 0; j < 4; ++j) {
            const size_t row = row0 + rt * 16 + (l >> 4) * 4 + j;
            vproj[row * NC + col] = (unsigned short)f2bf(acc[i][j] + bb);
        }
    }
}

// ---------------------------------------------------------------------------
// k_offattn: unchanged from round 1.
// ---------------------------------------------------------------------------
__global__ __launch_bounds__(128) void k_offattn(
    const float* __restrict__ query, const float* __restrict__ refp,
    const float* __restrict__ Woff, const float* __restrict__ boff,
    const float* __restrict__ Wattn, const float* __restrict__ battn,
    float* __restrict__ locs, float* __restrict__ attnw)
{
    const int t = threadIdx.x;
    const size_t q0 = (size_t)blockIdx.x * 16;

    __shared__ float qrow[16][NC];
    __shared__ float refs[16][2];
    {
        const float4* src = reinterpret_cast<const float4*>(query + q0 * NC);
        float4* dst = reinterpret_cast<float4*>(&qrow[0][0]);
#pragma unroll
        for (int i = 0; i < 8; ++i) dst[i * 128 + t] = src[i * 128 + t];
        if (t < 32) reinterpret_cast<float*>(refs)[t] = refp[q0 * 2 + t];
    }
    __syncthreads();

    const int c = t;
    const float* wp;
    int wstride;
    if (c < 64) { wp = Woff + c; wstride = 64; }
    else        { wp = Wattn + (c & 31); wstride = 32; }

    float acc[16];
#pragma unroll
    for (int r = 0; r < 16; ++r) acc[r] = 0.f;

    for (int k4 = 0; k4 < 64; ++k4) {
        float w0 = wp[(size_t)(k4 * 4 + 0) * wstride];
        float w1 = wp[(size_t)(k4 * 4 + 1) * wstride];
        float w2 = wp[(size_t)(k4 * 4 + 2) * wstride];
        float w3 = wp[(size_t)(k4 * 4 + 3) * wstride];
#pragma unroll
        for (int r = 0; r < 16; ++r) {
            const float4 a = *reinterpret_cast<const float4*>(&qrow[r][k4 * 4]);
            acc[r] = fmaf(a.x, w0, acc[r]);
            acc[r] = fmaf(a.y, w1, acc[r]);
            acc[r] = fmaf(a.z, w2, acc[r]);
            acc[r] = fmaf(a.w, w3, acc[r]);
        }
    }

    if (c < 64) {
        const float bias = boff[c];
        const int xy = c & 1;
#pragma unroll
        for (int r = 0; r < 16; ++r) {
            float off = acc[r] + bias;
            float loc = refs[r][xy] + off * (0.1f / 128.0f);
            loc = fminf(fmaxf(loc, 0.f), 1.f);
            locs[(q0 + r) * 64 + c] = loc;
        }
    } else if (c < 96) {
        const int lidx = c - 64;
        const float bias = battn[lidx];
#pragma unroll
        for (int r = 0; r < 16; ++r) {
            float v = acc[r] + bias;
            float m = fmaxf(v, __shfl_xor(v, 1));
            m = fmaxf(m, __shfl_xor(m, 2));
            float e = __expf(v - m);
            float s = e + __shfl_xor(e, 1);
            s = s + __shfl_xor(s, 2);
            attnw[(q0 + r) * 32 + lidx] = e / s;
        }
    }
}

// ---------------------------------------------------------------------------
// k_sample: gather (4 cols/lane, ushort4 loads) -> agg bf16 in swizzled LDS
// -> out-proj via MFMA.  block 256 thr / 4 waves, 16 queries.
// gather: wave w -> rows w*4..+3; lane: h=l>>3, dd0=(l&7)*4.
// mfma:   row-tile = 16 queries; wave w -> col-tiles w*4..+3.
// ---------------------------------------------------------------------------
__global__ __launch_bounds__(256) void k_sample(
    const unsigned short* __restrict__ vproj, const float* __restrict__ locs,
    const float* __restrict__ attnw, const unsigned short* __restrict__ Bpk,
    const float* __restrict__ bout, float* __restrict__ out)
{
    const int t = threadIdx.x;
    const int l = t & 63, w = t >> 6;
    const size_t q0 = (size_t)blockIdx.x * 16;
    const int b = (int)(q0 / NQ);

    __shared__ float locs_s[16][64];          // 4 KB
    __shared__ float attn_s[16][32];          // 2 KB
    __shared__ unsigned short agg[16 * 256];  // 8 KB, swizzled bf16

    {
        const float4* ls = reinterpret_cast<const float4*>(locs + q0 * 64);
        float4* ld = reinterpret_cast<float4*>(&locs_s[0][0]);
        ld[t] = ls[t];
        const float2* as = reinterpret_cast<const float2*>(attnw + q0 * 32);
        float2* ad = reinterpret_cast<float2*>(&attn_s[0][0]);
        ad[t] = as[t];
    }
    __syncthreads();

    const int h = l >> 3, dd0 = (l & 7) * 4;
    const unsigned short* __restrict__ vb =
        vproj + (size_t)b * NHW * NC + h * NHD + dd0;

#pragma unroll
    for (int rr = 0; rr < 4; ++rr) {
        const int r = w * 4 + rr;
        float a0 = 0.f, a1 = 0.f, a2 = 0.f, a3 = 0.f;
#pragma unroll
        for (int p = 0; p < 4; ++p) {
            const float lx = locs_s[r][h * 8 + p * 2 + 0];
            const float ly = locs_s[r][h * 8 + p * 2 + 1];
            const float aw = attn_s[r][h * 4 + p];
            const float x = lx * (float)IW - 0.5f;
            const float y = ly * (float)IH - 0.5f;
            const float x0f = floorf(x), y0f = floorf(y);
            const float wx = x - x0f, wy = y - y0f;
            const int ix0 = (int)x0f, iy0 = (int)y0f;
            const int ix1 = ix0 + 1, iy1 = iy0 + 1;
            const int cx0 = max(ix0, 0), cy0 = max(iy0, 0);
            const int cx1 = min(ix1, IW - 1), cy1 = min(iy1, IH - 1);
            const float vx0 = (ix0 >= 0) ? 1.f : 0.f;
            const float vy0 = (iy0 >= 0) ? 1.f : 0.f;
            const float vx1 = (ix1 < IW) ? 1.f : 0.f;
            const float vy1 = (iy1 < IH) ? 1.f : 0.f;
            const float w00 = aw * ((1.f - wx) * (1.f - wy) * vx0 * vy0);
            const float w01 = aw * (wx * (1.f - wy) * vx1 * vy0);
            const float w10 = aw * ((1.f - wx) * wy * vx0 * vy1);
            const float w11 = aw * (wx * wy * vx1 * vy1);
            const ushort4 v00 = *reinterpret_cast<const ushort4*>(vb + (size_t)(cy0 * IW + cx0) * NC);
            const ushort4 v01 = *reinterpret_cast<const ushort4*>(vb + (size_t)(cy0 * IW + cx1) * NC);
            const ushort4 v10 = *reinterpret_cast<const ushort4*>(vb + (size_t)(cy1 * IW + cx0) * NC);
            const ushort4 v11 = *reinterpret_cast<const ushort4*>(vb + (size_t)(cy1 * IW + cx1) * NC);
            a0 = fmaf(w00, bf2f(v00.x), a0); a0 = fmaf(w01, bf2f(v01.x), a0);
            a0 = fmaf(w10, bf2f(v10.x), a0); a0 = fmaf(w11, bf2f(v11.x), a0);
            a1 = fmaf(w00, bf2f(v00.y), a1); a1 = fmaf(w01, bf2f(v01.y), a1);
            a1 = fmaf(w10, bf2f(v10.y), a1); a1 = fmaf(w11, bf2f(v11.y), a1);
            a2 = fmaf(w00, bf2f(v00.z), a2); a2 = fmaf(w01, bf2f(v01.z), a2);
            a2 = fmaf(w10, bf2f(v10.z), a2); a2 = fmaf(w11, bf2f(v11.z), a2);
            a3 = fmaf(w00, bf2f(v00.w), a3); a3 = fmaf(w01, bf2f(v01.w), a3);
            a3 = fmaf(w10, bf2f(v10.w), a3); a3 = fmaf(w11, bf2f(v11.w), a3);
        }
        const unsigned int lo = f2bf(a0) | (f2bf(a1) << 16);
        const unsigned int hi = f2bf(a2) | (f2bf(a3) << 16);
        unsigned int byte = (unsigned int)(r * 512 + (h * NHD + dd0) * 2);
        byte ^= (unsigned int)((r & 7) << 4);
        *reinterpret_cast<uint2*>(reinterpret_cast<char*>(agg) + byte) = make_uint2(lo, hi);
    }
    __syncthreads();

    // out-projection MFMA: 16 queries x 256 cols, K = 256.
    const int arow = l & 15;
    const int achunk = l >> 4;
    f32x4 acc[4];
#pragma unroll
    for (int i = 0; i < 4; ++i) acc[i] = (f32x4)(0.f);

#pragma unroll
    for (int kt = 0; kt < 8; ++kt) {
        unsigned int abyte = (unsigned int)(arow * 512 + (kt * 32 + achunk * 8) * 2);
        abyte ^= (unsigned int)((arow & 7) << 4);
        FragCast af;
        af.q = *reinterpret_cast<const uint4*>(reinterpret_cast<const char*>(agg) + abyte);
        const unsigned short* bbase = Bpk + (size_t)kt * 8192 + (l & 15) * 32 + achunk * 8;
#pragma unroll
        for (int i = 0; i < 4; ++i) {
            const int ct = w * 4 + i;
            FragCast bf;
            bf.q = *reinterpret_cast<const uint4*>(bbase + ct * 512);
            acc[i] = __builtin_amdgcn_mfma_f32_16x16x32_bf16(af.v, bf.v, acc[i], 0, 0, 0);
        }
    }

#pragma unroll
    for (int i = 0; i < 4; ++i) {
        const int col = (w * 4 + i) * 16 + (l & 15);
        const float bb = bout[col];
#pragma unroll
        for (int j = 0; j < 4; ++j) {
            const size_t row = q0 + (l >> 4) * 4 + j;
            out[row * NC + col] = acc[i][j] + bb;
        }
    }
}

extern "C" void kernel_launch(void* const* d_in, const int* in_sizes, int n_in,
                              void* d_out, int out_size, void* d_ws, size_t ws_size,
                              hipStream_t stream) {
    const float* query = (const float*)d_in[0];
    const float* refp  = (const float*)d_in[1];
    const float* value = (const float*)d_in[2];
    const float* Woff  = (const float*)d_in[3];
    const float* boff  = (const float*)d_in[4];
    const float* Wattn = (const float*)d_in[5];
    const float* battn = (const float*)d_in[6];
    const float* Wv    = (const float*)d_in[7];
    const float* bv    = (const float*)d_in[8];
    const float* Wout  = (const float*)d_in[9];
    const float* bout  = (const float*)d_in[10];
    float* out = (float*)d_out;

    // workspace layout (bytes):
    unsigned short* vproj = (unsigned short*)d_ws;                   // 32 MB
    float* locs  = (float*)(vproj + (size_t)NB * NHW * NC);          //  8 MB
    float* attnw = locs + (size_t)NB * NQ * NHEADS * NP * 2;         //  4 MB
    unsigned short* WvPk  = (unsigned short*)(attnw + (size_t)NB * NQ * NHEADS * NP);
    unsigned short* WoutPk = WvPk + (size_t)NC * NC;                 // 128 KB each

    k_pack<<<dim3(16), dim3(256), 0, stream>>>(Wv, Wout, WvPk, WoutPk);
    k_vproj<<<dim3(NB * NHW / 32), dim3(256), 0, stream>>>(value, WvPk, bv, vproj);
    k_offattn<<<dim3(NB * NQ / 16), dim3(128), 0, stream>>>(query, refp, Woff, boff,
                                                            Wattn, battn, locs, attnw);
    k_sample<<<dim3(NB * NQ / 16), dim3(256), 0, stream>>>(vproj, locs, attnw, WoutPk, bout, out);
}

// Round 3
// 101.435 us; speedup vs baseline: 2.7231x; 1.3399x over previous
//
#include <hip/hip_runtime.h>
#include <cstdint>

#define NB 4
#define NQ 8192
#define NC 256
#define IH 128
#define IW 128
#define NHW (IH * IW)
#define NHEADS 8
#define NP 4
#define NHD 32

typedef __bf16 bf16x8 __attribute__((ext_vector_type(8)));
typedef float f32x4 __attribute__((ext_vector_type(4)));

union FragCast { uint4 q; bf16x8 v; };

__device__ __forceinline__ unsigned int f2bf(float f) {
    unsigned int u = __float_as_uint(f);
    return (u + 0x7FFFu + ((u >> 16) & 1u)) >> 16;
}
__device__ __forceinline__ float bf2f(unsigned short s) {
    return __uint_as_float(((unsigned int)s) << 16);
}

// ---------------------------------------------------------------------------
// k_pack: repack weights (f32, row-major [K][cols]) into bf16 MFMA B-fragment
// order pk[(kt*COLS + col)*32 + j] = bf16(W[(kt*32+j)*COLS + col]).
// tasks: 0..2047 Wv(256c), 2048..4095 Wout(256c), 4096..4863 [Woff|Wattn](96c)
// ---------------------------------------------------------------------------
__global__ __launch_bounds__(256) void k_pack(
    const float* __restrict__ Wv, const float* __restrict__ Wout,
    const float* __restrict__ Woff, const float* __restrict__ Wattn,
    unsigned short* __restrict__ pkv, unsigned short* __restrict__ pko,
    unsigned short* __restrict__ pkq)
{
    const int tid = blockIdx.x * 256 + threadIdx.x;   // 0..4863
    if (tid < 4096) {
        const float* src = (tid & 2048) ? Wout : Wv;
        unsigned short* dst = (tid & 2048) ? pko : pkv;
        const int rem = tid & 2047;
        const int kt = rem >> 8, col = rem & 255;
        unsigned short* d = dst + (size_t)(kt * 256 + col) * 32;
        const float* s = src + (size_t)kt * 32 * 256 + col;
#pragma unroll
        for (int j = 0; j < 32; ++j)
            d[j] = (unsigned short)f2bf(s[(size_t)j * 256]);
    } else {
        const int rem = tid - 4096;       // 0..767
        const int kt = rem / 96, col = rem % 96;
        unsigned short* d = pkq + (size_t)(kt * 96 + col) * 32;
        const float* s; int stride;
        if (col < 64) { s = Woff + col; stride = 64; }
        else          { s = Wattn + (col - 64); stride = 32; }
        s += (size_t)kt * 32 * stride;
#pragma unroll
        for (int j = 0; j < 32; ++j)
            d[j] = (unsigned short)f2bf(s[(size_t)j * stride]);
    }
}

// ---------------------------------------------------------------------------
// k_vproj (MFMA): vproj[b,pix,:] = bf16(value[b,pix,:] @ Wv + bv)
// ---------------------------------------------------------------------------
__global__ __launch_bounds__(256) void k_vproj(
    const float* __restrict__ value, const unsigned short* __restrict__ Bpk,
    const float* __restrict__ bv, unsigned short* __restrict__ vproj)
{
    const int t = threadIdx.x;
    const int l = t & 63, w = t >> 6;
    const size_t row0 = (size_t)blockIdx.x * 32;

    __shared__ unsigned short A[32 * 256];  // 16 KB, swizzled bf16

#pragma unroll
    for (int i = 0; i < 8; ++i) {
        const int chunk = i * 256 + t;
        const int row = chunk >> 6;
        const int k0 = (chunk & 63) * 4;
        const float4 v4 = *reinterpret_cast<const float4*>(&value[(row0 + row) * NC + k0]);
        const unsigned int lo = f2bf(v4.x) | (f2bf(v4.y) << 16);
        const unsigned int hi = f2bf(v4.z) | (f2bf(v4.w) << 16);
        unsigned int byte = (unsigned int)(row * 512 + k0 * 2);
        byte ^= (unsigned int)((row & 7) << 4);
        *reinterpret_cast<uint2*>(reinterpret_cast<char*>(A) + byte) = make_uint2(lo, hi);
    }
    __syncthreads();

    const int rt = w & 1, cg = w >> 1;
    const int arow = rt * 16 + (l & 15);
    const int achunk = l >> 4;

    f32x4 acc[8];
#pragma unroll
    for (int i = 0; i < 8; ++i) acc[i] = (f32x4)(0.f);

#pragma unroll
    for (int kt = 0; kt < 8; ++kt) {
        unsigned int abyte = (unsigned int)(arow * 512 + (kt * 32 + achunk * 8) * 2);
        abyte ^= (unsigned int)((arow & 7) << 4);
        FragCast af;
        af.q = *reinterpret_cast<const uint4*>(reinterpret_cast<const char*>(A) + abyte);
        const unsigned short* bbase = Bpk + (size_t)kt * 8192 + (l & 15) * 32 + achunk * 8;
#pragma unroll
        for (int i = 0; i < 8; ++i) {
            const int ct = cg * 8 + i;
            FragCast bf;
            bf.q = *reinterpret_cast<const uint4*>(bbase + ct * 512);
            acc[i] = __builtin_amdgcn_mfma_f32_16x16x32_bf16(af.v, bf.v, acc[i], 0, 0, 0);
        }
    }

#pragma unroll
    for (int i = 0; i < 8; ++i) {
        const int col = (cg * 8 + i) * 16 + (l & 15);
        const float bb = bv[col];
#pragma unroll
        for (int j = 0; j < 4; ++j) {
            const size_t row = row0 + rt * 16 + (l >> 4) * 4 + j;
            vproj[row * NC + col] = (unsigned short)f2bf(acc[i][j] + bb);
        }
    }
}

// ---------------------------------------------------------------------------
// k_offattn (MFMA): [offsets|attn-logits] = query @ [Woff|Wattn] + bias,
// then loc-clip / P=4 softmax epilogue.  32 queries/block, 256 thr / 4 waves.
// wave w: row-tile rt=w>>1 (16 rows), col-tiles ct=(w&1)*3 .. +2 (of 6).
// ---------------------------------------------------------------------------
__global__ __launch_bounds__(256) void k_offattn(
    const float* __restrict__ query, const float* __restrict__ refp,
    const unsigned short* __restrict__ Bpk, const float* __restrict__ boff,
    const float* __restrict__ battn,
    float* __restrict__ locs, float* __restrict__ attnw)
{
    const int t = threadIdx.x;
    const int l = t & 63, w = t >> 6;
    const size_t q0 = (size_t)blockIdx.x * 32;

    __shared__ unsigned short A[32 * 256];  // 16 KB, swizzled bf16
    __shared__ float refs[32][2];

#pragma unroll
    for (int i = 0; i < 8; ++i) {
        const int chunk = i * 256 + t;
        const int row = chunk >> 6;
        const int k0 = (chunk & 63) * 4;
        const float4 v4 = *reinterpret_cast<const float4*>(&query[(q0 + row) * NC + k0]);
        const unsigned int lo = f2bf(v4.x) | (f2bf(v4.y) << 16);
        const unsigned int hi = f2bf(v4.z) | (f2bf(v4.w) << 16);
        unsigned int byte = (unsigned int)(row * 512 + k0 * 2);
        byte ^= (unsigned int)((row & 7) << 4);
        *reinterpret_cast<uint2*>(reinterpret_cast<char*>(A) + byte) = make_uint2(lo, hi);
    }
    if (t < 64) reinterpret_cast<float*>(refs)[t] = refp[q0 * 2 + t];
    __syncthreads();

    const int rt = w >> 1, ctbase = (w & 1) * 3;
    const int arow = rt * 16 + (l & 15);
    const int achunk = l >> 4;

    f32x4 acc[3];
#pragma unroll
    for (int i = 0; i < 3; ++i) acc[i] = (f32x4)(0.f);

#pragma unroll
    for (int kt = 0; kt < 8; ++kt) {
        unsigned int abyte = (unsigned int)(arow * 512 + (kt * 32 + achunk * 8) * 2);
        abyte ^= (unsigned int)((arow & 7) << 4);
        FragCast af;
        af.q = *reinterpret_cast<const uint4*>(reinterpret_cast<const char*>(A) + abyte);
        const unsigned short* bbase = Bpk + (size_t)kt * (96 * 32) + (l & 15) * 32 + achunk * 8;
#pragma unroll
        for (int i = 0; i < 3; ++i) {
            const int ct = ctbase + i;
            FragCast bf;
            bf.q = *reinterpret_cast<const uint4*>(bbase + ct * 512);
            acc[i] = __builtin_amdgcn_mfma_f32_16x16x32_bf16(af.v, bf.v, acc[i], 0, 0, 0);
        }
    }

#pragma unroll
    for (int i = 0; i < 3; ++i) {
        const int col = (ctbase + i) * 16 + (l & 15);
        if (col < 64) {
            const float bias = boff[col];
            const int xy = col & 1;
#pragma unroll
            for (int j = 0; j < 4; ++j) {
                const int row = rt * 16 + (l >> 4) * 4 + j;
                float off = acc[i][j] + bias;
                float loc = refs[row][xy] + off * (0.1f / 128.0f);
                loc = fminf(fmaxf(loc, 0.f), 1.f);
                locs[(q0 + row) * 64 + col] = loc;
            }
        } else {
            const int lc = col - 64;               // lc = h*4 + p, p = l&3
            const float bias = battn[lc];
#pragma unroll
            for (int j = 0; j < 4; ++j) {
                const int row = rt * 16 + (l >> 4) * 4 + j;
                float v = acc[i][j] + bias;
                float m = fmaxf(v, __shfl_xor(v, 1));
                m = fmaxf(m, __shfl_xor(m, 2));
                float e = __expf(v - m);
                float s = e + __shfl_xor(e, 1);
                s = s + __shfl_xor(s, 2);
                attnw[(q0 + row) * 32 + lc] = e / s;
            }
        }
    }
}

// ---------------------------------------------------------------------------
// k_sample: gather (4 cols/lane, ushort4 loads) -> agg bf16 in swizzled LDS
// -> out-proj via MFMA.  block 256 thr / 4 waves, 16 queries.
// ---------------------------------------------------------------------------
__global__ __launch_bounds__(256) void k_sample(
    const unsigned short* __restrict__ vproj, const float* __restrict__ locs,
    const float* __restrict__ attnw, const unsigned short* __restrict__ Bpk,
    const float* __restrict__ bout, float* __restrict__ out)
{
    const int t = threadIdx.x;
    const int l = t & 63, w = t >> 6;
    const size_t q0 = (size_t)blockIdx.x * 16;
    const int b = (int)(q0 / NQ);

    __shared__ float locs_s[16][64];          // 4 KB
    __shared__ float attn_s[16][32];          // 2 KB
    __shared__ unsigned short agg[16 * 256];  // 8 KB, swizzled bf16

    {
        const float4* ls = reinterpret_cast<const float4*>(locs + q0 * 64);
        float4* ld = reinterpret_cast<float4*>(&locs_s[0][0]);
        ld[t] = ls[t];
        const float2* as = reinterpret_cast<const float2*>(attnw + q0 * 32);
        float2* ad = reinterpret_cast<float2*>(&attn_s[0][0]);
        ad[t] = as[t];
    }
    __syncthreads();

    const int h = l >> 3, dd0 = (l & 7) * 4;
    const unsigned short* __restrict__ vb =
        vproj + (size_t)b * NHW * NC + h * NHD + dd0;

#pragma unroll
    for (int rr = 0; rr < 4; ++rr) {
        const int r = w * 4 + rr;
        float a0 = 0.f, a1 = 0.f, a2 = 0.f, a3 = 0.f;
#pragma unroll
        for (int p = 0; p < 4; ++p) {
            const float lx = locs_s[r][h * 8 + p * 2 + 0];
            const float ly = locs_s[r][h * 8 + p * 2 + 1];
            const float aw = attn_s[r][h * 4 + p];
            const float x = lx * (float)IW - 0.5f;
            const float y = ly * (float)IH - 0.5f;
            const float x0f = floorf(x), y0f = floorf(y);
            const float wx = x - x0f, wy = y - y0f;
            const int ix0 = (int)x0f, iy0 = (int)y0f;
            const int ix1 = ix0 + 1, iy1 = iy0 + 1;
            const int cx0 = max(ix0, 0), cy0 = max(iy0, 0);
            const int cx1 = min(ix1, IW - 1), cy1 = min(iy1, IH - 1);
            const float vx0 = (ix0 >= 0) ? 1.f : 0.f;
            const float vy0 = (iy0 >= 0) ? 1.f : 0.f;
            const float vx1 = (ix1 < IW) ? 1.f : 0.f;
            const float vy1 = (iy1 < IH) ? 1.f : 0.f;
            const float w00 = aw * ((1.f - wx) * (1.f - wy) * vx0 * vy0);
            const float w01 = aw * (wx * (1.f - wy) * vx1 * vy0);
            const float w10 = aw * ((1.f - wx) * wy * vx0 * vy1);
            const float w11 = aw * (wx * wy * vx1 * vy1);
            const ushort4 v00 = *reinterpret_cast<const ushort4*>(vb + (size_t)(cy0 * IW + cx0) * NC);
            const ushort4 v01 = *reinterpret_cast<const ushort4*>(vb + (size_t)(cy0 * IW + cx1) * NC);
            const ushort4 v10 = *reinterpret_cast<const ushort4*>(vb + (size_t)(cy1 * IW + cx0) * NC);
            const ushort4 v11 = *reinterpret_cast<const ushort4*>(vb + (size_t)(cy1 * IW + cx1) * NC);
            a0 = fmaf(w00, bf2f(v00.x), a0); a0 = fmaf(w01, bf2f(v01.x), a0);
            a0 = fmaf(w10, bf2f(v10.x), a0); a0 = fmaf(w11, bf2f(v11.x), a0);
            a1 = fmaf(w00, bf2f(v00.y), a1); a1 = fmaf(w01, bf2f(v01.y), a1);
            a1 = fmaf(w10, bf2f(v10.y), a1); a1 = fmaf(w11, bf2f(v11.y), a1);
            a2 = fmaf(w00, bf2f(v00.z), a2); a2 = fmaf(w01, bf2f(v01.z), a2);
            a2 = fmaf(w10, bf2f(v10.z), a2); a2 = fmaf(w11, bf2f(v11.z), a2);
            a3 = fmaf(w00, bf2f(v00.w), a3); a3 = fmaf(w01, bf2f(v01.w), a3);
            a3 = fmaf(w10, bf2f(v10.w), a3); a3 = fmaf(w11, bf2f(v11.w), a3);
        }
        const unsigned int lo = f2bf(a0) | (f2bf(a1) << 16);
        const unsigned int hi = f2bf(a2) | (f2bf(a3) << 16);
        unsigned int byte = (unsigned int)(r * 512 + (h * NHD + dd0) * 2);
        byte ^= (unsigned int)((r & 7) << 4);
        *reinterpret_cast<uint2*>(reinterpret_cast<char*>(agg) + byte) = make_uint2(lo, hi);
    }
    __syncthreads();

    const int arow = l & 15;
    const int achunk = l >> 4;
    f32x4 acc[4];
#pragma unroll
    for (int i = 0; i < 4; ++i) acc[i] = (f32x4)(0.f);

#pragma unroll
    for (int kt = 0; kt < 8; ++kt) {
        unsigned int abyte = (unsigned int)(arow * 512 + (kt * 32 + achunk * 8) * 2);
        abyte ^= (unsigned int)((arow & 7) << 4);
        FragCast af;
        af.q = *reinterpret_cast<const uint4*>(reinterpret_cast<const char*>(agg) + abyte);
        const unsigned short* bbase = Bpk + (size_t)kt * 8192 + (l & 15) * 32 + achunk * 8;
#pragma unroll
        for (int i = 0; i < 4; ++i) {
            const int ct = w * 4 + i;
            FragCast bf;
            bf.q = *reinterpret_cast<const uint4*>(bbase + ct * 512);
            acc[i] = __builtin_amdgcn_mfma_f32_16x16x32_bf16(af.v, bf.v, acc[i], 0, 0, 0);
        }
    }

#pragma unroll
    for (int i = 0; i < 4; ++i) {
        const int col = (w * 4 + i) * 16 + (l & 15);
        const float bb = bout[col];
#pragma unroll
        for (int j = 0; j < 4; ++j) {
            const size_t row = q0 + (l >> 4) * 4 + j;
            out[row * NC + col] = acc[i][j] + bb;
        }
    }
}

extern "C" void kernel_launch(void* const* d_in, const int* in_sizes, int n_in,
                              void* d_out, int out_size, void* d_ws, size_t ws_size,
                              hipStream_t stream) {
    const float* query = (const float*)d_in[0];
    const float* refp  = (const float*)d_in[1];
    const float* value = (const float*)d_in[2];
    const float* Woff  = (const float*)d_in[3];
    const float* boff  = (const float*)d_in[4];
    const float* Wattn = (const float*)d_in[5];
    const float* battn = (const float*)d_in[6];
    const float* Wv    = (const float*)d_in[7];
    const float* bv    = (const float*)d_in[8];
    const float* Wout  = (const float*)d_in[9];
    const float* bout  = (const float*)d_in[10];
    float* out = (float*)d_out;

    unsigned short* vproj = (unsigned short*)d_ws;                   // 32 MB
    float* locs  = (float*)(vproj + (size_t)NB * NHW * NC);          //  8 MB
    float* attnw = locs + (size_t)NB * NQ * NHEADS * NP * 2;         //  4 MB
    unsigned short* WvPk   = (unsigned short*)(attnw + (size_t)NB * NQ * NHEADS * NP);
    unsigned short* WoutPk = WvPk + (size_t)NC * NC;                 // 128 KB each
    unsigned short* WqPk   = WoutPk + (size_t)NC * NC;               //  48 KB

    k_pack<<<dim3(19), dim3(256), 0, stream>>>(Wv, Wout, Woff, Wattn, WvPk, WoutPk, WqPk);
    k_vproj<<<dim3(NB * NHW / 32), dim3(256), 0, stream>>>(value, WvPk, bv, vproj);
    k_offattn<<<dim3(NB * NQ / 32), dim3(256), 0, stream>>>(query, refp, WqPk, boff,
                                                            battn, locs, attnw);
    k_sample<<<dim3(NB * NQ / 16), dim3(256), 0, stream>>>(vproj, locs, attnw, WoutPk, bout, out);
}

// Round 4
// 82.720 us; speedup vs baseline: 3.3391x; 1.2262x over previous
//
#include <hip/hip_runtime.h>
#include <cstdint>

#define NB 4
#define NQ 8192
#define NC 256
#define IH 128
#define IW 128
#define NHW (IH * IW)
#define NHEADS 8
#define NP 4
#define NHD 32

typedef __bf16 bf16x8 __attribute__((ext_vector_type(8)));
typedef float f32x4 __attribute__((ext_vector_type(4)));

union FragCast { uint4 q; bf16x8 v; };

__device__ __forceinline__ unsigned int f2bf(float f) {
    unsigned int u = __float_as_uint(f);
    return (u + 0x7FFFu + ((u >> 16) & 1u)) >> 16;
}
__device__ __forceinline__ float bf2f(unsigned short s) {
    return __uint_as_float(((unsigned int)s) << 16);
}

// ---------------------------------------------------------------------------
// k_pack: repack weights (f32, row-major [K][cols]) into bf16 MFMA B-fragment
// order pk[(kt*COLS + col)*32 + j] = bf16(W[(kt*32+j)*COLS + col]).
// ---------------------------------------------------------------------------
__global__ __launch_bounds__(256) void k_pack(
    const float* __restrict__ Wv, const float* __restrict__ Wout,
    const float* __restrict__ Woff, const float* __restrict__ Wattn,
    unsigned short* __restrict__ pkv, unsigned short* __restrict__ pko,
    unsigned short* __restrict__ pkq)
{
    const int tid = blockIdx.x * 256 + threadIdx.x;   // 0..4863
    if (tid < 4096) {
        const float* src = (tid & 2048) ? Wout : Wv;
        unsigned short* dst = (tid & 2048) ? pko : pkv;
        const int rem = tid & 2047;
        const int kt = rem >> 8, col = rem & 255;
        unsigned short* d = dst + (size_t)(kt * 256 + col) * 32;
        const float* s = src + (size_t)kt * 32 * 256 + col;
#pragma unroll
        for (int j = 0; j < 32; ++j)
            d[j] = (unsigned short)f2bf(s[(size_t)j * 256]);
    } else {
        const int rem = tid - 4096;       // 0..767
        const int kt = rem / 96, col = rem % 96;
        unsigned short* d = pkq + (size_t)(kt * 96 + col) * 32;
        const float* s; int stride;
        if (col < 64) { s = Woff + col; stride = 64; }
        else          { s = Wattn + (col - 64); stride = 32; }
        s += (size_t)kt * 32 * stride;
#pragma unroll
        for (int j = 0; j < 32; ++j)
            d[j] = (unsigned short)f2bf(s[(size_t)j * stride]);
    }
}

// ---------------------------------------------------------------------------
// k_vproj v2: 256 blocks x 512 thr (8 waves). Block processes 4 tiles of 64
// rows. Wave w: row-half mh=w&1 (2 m-frags), col-group cg=w>>1 (cols cg*64,
// 4 cts). B fragments held in registers (loaded once). A double-buffered in
// swizzled LDS; next-tile global loads issued before compute (T14).
// ---------------------------------------------------------------------------
#define VP_TPB 4
__global__ __launch_bounds__(512) void k_vproj(
    const float* __restrict__ value, const unsigned short* __restrict__ Bpk,
    const float* __restrict__ bv, unsigned short* __restrict__ vproj)
{
    const int t = threadIdx.x;
    const int l = t & 63, w = t >> 6;
    const int mh = w & 1, cg = w >> 1;

    __shared__ unsigned short A[2][64 * 256];   // 2 x 32 KB swizzled bf16

    // B fragments: bq[kt][i] for ct = cg*4+i  (128 VGPR)
    uint4 bq[8][4];
#pragma unroll
    for (int kt = 0; kt < 8; ++kt)
#pragma unroll
        for (int i = 0; i < 4; ++i)
            bq[kt][i] = *reinterpret_cast<const uint4*>(
                Bpk + (size_t)kt * 8192 + (size_t)(cg * 4 + i) * 512 +
                (l & 15) * 32 + (l >> 4) * 8);

    float bb[4];
#pragma unroll
    for (int i = 0; i < 4; ++i) bb[i] = bv[cg * 64 + i * 16 + (l & 15)];

    const size_t tile0 = (size_t)blockIdx.x * VP_TPB;

    float4 st[8];
    // prologue: load + write tile 0
#pragma unroll
    for (int i = 0; i < 8; ++i) {
        const int chunk = i * 512 + t;
        const int row = chunk >> 6, k0 = (chunk & 63) * 4;
        st[i] = *reinterpret_cast<const float4*>(&value[(tile0 * 64 + row) * NC + k0]);
    }
#pragma unroll
    for (int i = 0; i < 8; ++i) {
        const int chunk = i * 512 + t;
        const int row = chunk >> 6, k0 = (chunk & 63) * 4;
        unsigned int byte = (unsigned int)(row * 512 + k0 * 2) ^ (unsigned int)((row & 7) << 4);
        *reinterpret_cast<uint2*>(reinterpret_cast<char*>(A[0]) + byte) =
            make_uint2(f2bf(st[i].x) | (f2bf(st[i].y) << 16),
                       f2bf(st[i].z) | (f2bf(st[i].w) << 16));
    }
    __syncthreads();

    for (int tt = 0; tt < VP_TPB; ++tt) {
        const int cur = tt & 1;
        if (tt + 1 < VP_TPB) {
#pragma unroll
            for (int i = 0; i < 8; ++i) {
                const int chunk = i * 512 + t;
                const int row = chunk >> 6, k0 = (chunk & 63) * 4;
                st[i] = *reinterpret_cast<const float4*>(
                    &value[((tile0 + tt + 1) * 64 + row) * NC + k0]);
            }
        }

        f32x4 acc[2][4];
#pragma unroll
        for (int m = 0; m < 2; ++m)
#pragma unroll
            for (int i = 0; i < 4; ++i) acc[m][i] = (f32x4)(bb[i]);

#pragma unroll
        for (int kt = 0; kt < 8; ++kt) {
#pragma unroll
            for (int m = 0; m < 2; ++m) {
                const int arow = mh * 32 + m * 16 + (l & 15);
                unsigned int abyte = (unsigned int)(arow * 512 + (kt * 32 + (l >> 4) * 8) * 2)
                                   ^ (unsigned int)((arow & 7) << 4);
                FragCast af;
                af.q = *reinterpret_cast<const uint4*>(reinterpret_cast<const char*>(A[cur]) + abyte);
#pragma unroll
                for (int i = 0; i < 4; ++i) {
                    FragCast bfc; bfc.q = bq[kt][i];
                    acc[m][i] = __builtin_amdgcn_mfma_f32_16x16x32_bf16(af.v, bfc.v, acc[m][i], 0, 0, 0);
                }
            }
        }

        const size_t rowbase = (tile0 + tt) * 64;
#pragma unroll
        for (int m = 0; m < 2; ++m)
#pragma unroll
            for (int i = 0; i < 4; ++i) {
                const int col = cg * 64 + i * 16 + (l & 15);
#pragma unroll
                for (int j = 0; j < 4; ++j) {
                    const size_t row = rowbase + mh * 32 + m * 16 + (l >> 4) * 4 + j;
                    vproj[row * NC + col] = (unsigned short)f2bf(acc[m][i][j]);
                }
            }

        if (tt + 1 < VP_TPB) {
#pragma unroll
            for (int i = 0; i < 8; ++i) {
                const int chunk = i * 512 + t;
                const int row = chunk >> 6, k0 = (chunk & 63) * 4;
                unsigned int byte = (unsigned int)(row * 512 + k0 * 2) ^ (unsigned int)((row & 7) << 4);
                *reinterpret_cast<uint2*>(reinterpret_cast<char*>(A[cur ^ 1]) + byte) =
                    make_uint2(f2bf(st[i].x) | (f2bf(st[i].y) << 16),
                               f2bf(st[i].z) | (f2bf(st[i].w) << 16));
            }
            __syncthreads();
        }
    }
}

// ---------------------------------------------------------------------------
// k_offattn (MFMA): unchanged from round 3.
// ---------------------------------------------------------------------------
__global__ __launch_bounds__(256) void k_offattn(
    const float* __restrict__ query, const float* __restrict__ refp,
    const unsigned short* __restrict__ Bpk, const float* __restrict__ boff,
    const float* __restrict__ battn,
    float* __restrict__ locs, float* __restrict__ attnw)
{
    const int t = threadIdx.x;
    const int l = t & 63, w = t >> 6;
    const size_t q0 = (size_t)blockIdx.x * 32;

    __shared__ unsigned short A[32 * 256];
    __shared__ float refs[32][2];

#pragma unroll
    for (int i = 0; i < 8; ++i) {
        const int chunk = i * 256 + t;
        const int row = chunk >> 6;
        const int k0 = (chunk & 63) * 4;
        const float4 v4 = *reinterpret_cast<const float4*>(&query[(q0 + row) * NC + k0]);
        const unsigned int lo = f2bf(v4.x) | (f2bf(v4.y) << 16);
        const unsigned int hi = f2bf(v4.z) | (f2bf(v4.w) << 16);
        unsigned int byte = (unsigned int)(row * 512 + k0 * 2);
        byte ^= (unsigned int)((row & 7) << 4);
        *reinterpret_cast<uint2*>(reinterpret_cast<char*>(A) + byte) = make_uint2(lo, hi);
    }
    if (t < 64) reinterpret_cast<float*>(refs)[t] = refp[q0 * 2 + t];
    __syncthreads();

    const int rt = w >> 1, ctbase = (w & 1) * 3;
    const int arow = rt * 16 + (l & 15);
    const int achunk = l >> 4;

    f32x4 acc[3];
#pragma unroll
    for (int i = 0; i < 3; ++i) acc[i] = (f32x4)(0.f);

#pragma unroll
    for (int kt = 0; kt < 8; ++kt) {
        unsigned int abyte = (unsigned int)(arow * 512 + (kt * 32 + achunk * 8) * 2);
        abyte ^= (unsigned int)((arow & 7) << 4);
        FragCast af;
        af.q = *reinterpret_cast<const uint4*>(reinterpret_cast<const char*>(A) + abyte);
        const unsigned short* bbase = Bpk + (size_t)kt * (96 * 32) + (l & 15) * 32 + achunk * 8;
#pragma unroll
        for (int i = 0; i < 3; ++i) {
            const int ct = ctbase + i;
            FragCast bfc;
            bfc.q = *reinterpret_cast<const uint4*>(bbase + ct * 512);
            acc[i] = __builtin_amdgcn_mfma_f32_16x16x32_bf16(af.v, bfc.v, acc[i], 0, 0, 0);
        }
    }

#pragma unroll
    for (int i = 0; i < 3; ++i) {
        const int col = (ctbase + i) * 16 + (l & 15);
        if (col < 64) {
            const float bias = boff[col];
            const int xy = col & 1;
#pragma unroll
            for (int j = 0; j < 4; ++j) {
                const int row = rt * 16 + (l >> 4) * 4 + j;
                float off = acc[i][j] + bias;
                float loc = refs[row][xy] + off * (0.1f / 128.0f);
                loc = fminf(fmaxf(loc, 0.f), 1.f);
                locs[(q0 + row) * 64 + col] = loc;
            }
        } else {
            const int lc = col - 64;
            const float bias = battn[lc];
#pragma unroll
            for (int j = 0; j < 4; ++j) {
                const int row = rt * 16 + (l >> 4) * 4 + j;
                float v = acc[i][j] + bias;
                float m = fmaxf(v, __shfl_xor(v, 1));
                m = fmaxf(m, __shfl_xor(m, 2));
                float e = __expf(v - m);
                float s = e + __shfl_xor(e, 1);
                s = s + __shfl_xor(s, 2);
                attnw[(q0 + row) * 32 + lc] = e / s;
            }
        }
    }
}

// ---------------------------------------------------------------------------
// k_sample v2: gather with 16B (ushort8) loads, 16 corner loads batched per
// (row, head, col-oct); lane l -> rhalf=l>>5, h=(l>>2)&7, c=l&3 (cols c*8..+7).
// Then agg bf16 swizzled LDS -> out-proj MFMA (unchanged).
// ---------------------------------------------------------------------------
__global__ __launch_bounds__(256) void k_sample(
    const unsigned short* __restrict__ vproj, const float* __restrict__ locs,
    const float* __restrict__ attnw, const unsigned short* __restrict__ Bpk,
    const float* __restrict__ bout, float* __restrict__ out)
{
    const int t = threadIdx.x;
    const int l = t & 63, w = t >> 6;
    const size_t q0 = (size_t)blockIdx.x * 16;
    const int b = (int)(q0 / NQ);

    __shared__ float locs_s[16][64];
    __shared__ float attn_s[16][32];
    __shared__ unsigned short agg[16 * 256];

    {
        const float4* ls = reinterpret_cast<const float4*>(locs + q0 * 64);
        float4* ld = reinterpret_cast<float4*>(&locs_s[0][0]);
        ld[t] = ls[t];
        const float2* as = reinterpret_cast<const float2*>(attnw + q0 * 32);
        float2* ad = reinterpret_cast<float2*>(&attn_s[0][0]);
        ad[t] = as[t];
    }
    __syncthreads();

    const int rhalf = l >> 5, h = (l >> 2) & 7, c = l & 3;
    const unsigned short* __restrict__ vb =
        vproj + (size_t)b * NHW * NC + h * NHD + c * 8;

#pragma unroll
    for (int it = 0; it < 2; ++it) {
        const int r = w * 4 + it * 2 + rhalf;
        float wts[16];
        uint4 vals[16];
#pragma unroll
        for (int p = 0; p < 4; ++p) {
            const float lx = locs_s[r][h * 8 + p * 2 + 0];
            const float ly = locs_s[r][h * 8 + p * 2 + 1];
            const float aw = attn_s[r][h * 4 + p];
            const float x = lx * (float)IW - 0.5f;
            const float y = ly * (float)IH - 0.5f;
            const float x0f = floorf(x), y0f = floorf(y);
            const float wx = x - x0f, wy = y - y0f;
            const int ix0 = (int)x0f, iy0 = (int)y0f;
            const int ix1 = ix0 + 1, iy1 = iy0 + 1;
            const int cx0 = max(ix0, 0), cy0 = max(iy0, 0);
            const int cx1 = min(ix1, IW - 1), cy1 = min(iy1, IH - 1);
            const float vx0 = (ix0 >= 0) ? 1.f : 0.f;
            const float vy0 = (iy0 >= 0) ? 1.f : 0.f;
            const float vx1 = (ix1 < IW) ? 1.f : 0.f;
            const float vy1 = (iy1 < IH) ? 1.f : 0.f;
            wts[p * 4 + 0] = aw * ((1.f - wx) * (1.f - wy) * vx0 * vy0);
            wts[p * 4 + 1] = aw * (wx * (1.f - wy) * vx1 * vy0);
            wts[p * 4 + 2] = aw * ((1.f - wx) * wy * vx0 * vy1);
            wts[p * 4 + 3] = aw * (wx * wy * vx1 * vy1);
            vals[p * 4 + 0] = *reinterpret_cast<const uint4*>(vb + (size_t)(cy0 * IW + cx0) * NC);
            vals[p * 4 + 1] = *reinterpret_cast<const uint4*>(vb + (size_t)(cy0 * IW + cx1) * NC);
            vals[p * 4 + 2] = *reinterpret_cast<const uint4*>(vb + (size_t)(cy1 * IW + cx0) * NC);
            vals[p * 4 + 3] = *reinterpret_cast<const uint4*>(vb + (size_t)(cy1 * IW + cx1) * NC);
        }
        float acc[8];
#pragma unroll
        for (int e = 0; e < 8; ++e) acc[e] = 0.f;
#pragma unroll
        for (int j = 0; j < 16; ++j) {
            const unsigned short* u = reinterpret_cast<const unsigned short*>(&vals[j]);
            const float wj = wts[j];
#pragma unroll
            for (int e = 0; e < 8; ++e) acc[e] = fmaf(wj, bf2f(u[e]), acc[e]);
        }
        uint4 pk;
        pk.x = f2bf(acc[0]) | (f2bf(acc[1]) << 16);
        pk.y = f2bf(acc[2]) | (f2bf(acc[3]) << 16);
        pk.z = f2bf(acc[4]) | (f2bf(acc[5]) << 16);
        pk.w = f2bf(acc[6]) | (f2bf(acc[7]) << 16);
        unsigned int byte = (unsigned int)(r * 512 + (h * NHD + c * 8) * 2);
        byte ^= (unsigned int)((r & 7) << 4);
        *reinterpret_cast<uint4*>(reinterpret_cast<char*>(agg) + byte) = pk;
    }
    __syncthreads();

    const int arow = l & 15;
    const int achunk = l >> 4;
    f32x4 acc2[4];
#pragma unroll
    for (int i = 0; i < 4; ++i) acc2[i] = (f32x4)(0.f);

#pragma unroll
    for (int kt = 0; kt < 8; ++kt) {
        unsigned int abyte = (unsigned int)(arow * 512 + (kt * 32 + achunk * 8) * 2);
        abyte ^= (unsigned int)((arow & 7) << 4);
        FragCast af;
        af.q = *reinterpret_cast<const uint4*>(reinterpret_cast<const char*>(agg) + abyte);
        const unsigned short* bbase = Bpk + (size_t)kt * 8192 + (l & 15) * 32 + achunk * 8;
#pragma unroll
        for (int i = 0; i < 4; ++i) {
            const int ct = w * 4 + i;
            FragCast bfc;
            bfc.q = *reinterpret_cast<const uint4*>(bbase + ct * 512);
            acc2[i] = __builtin_amdgcn_mfma_f32_16x16x32_bf16(af.v, bfc.v, acc2[i], 0, 0, 0);
        }
    }

#pragma unroll
    for (int i = 0; i < 4; ++i) {
        const int col = (w * 4 + i) * 16 + (l & 15);
        const float bbv = bout[col];
#pragma unroll
        for (int j = 0; j < 4; ++j) {
            const size_t row = q0 + (l >> 4) * 4 + j;
            out[row * NC + col] = acc2[i][j] + bbv;
        }
    }
}

extern "C" void kernel_launch(void* const* d_in, const int* in_sizes, int n_in,
                              void* d_out, int out_size, void* d_ws, size_t ws_size,
                              hipStream_t stream) {
    const float* query = (const float*)d_in[0];
    const float* refp  = (const float*)d_in[1];
    const float* value = (const float*)d_in[2];
    const float* Woff  = (const float*)d_in[3];
    const float* boff  = (const float*)d_in[4];
    const float* Wattn = (const float*)d_in[5];
    const float* battn = (const float*)d_in[6];
    const float* Wv    = (const float*)d_in[7];
    const float* bv    = (const float*)d_in[8];
    const float* Wout  = (const float*)d_in[9];
    const float* bout  = (const float*)d_in[10];
    float* out = (float*)d_out;

    unsigned short* vproj = (unsigned short*)d_ws;                   // 32 MB
    float* locs  = (float*)(vproj + (size_t)NB * NHW * NC);          //  8 MB
    float* attnw = locs + (size_t)NB * NQ * NHEADS * NP * 2;         //  4 MB
    unsigned short* WvPk   = (unsigned short*)(attnw + (size_t)NB * NQ * NHEADS * NP);
    unsigned short* WoutPk = WvPk + (size_t)NC * NC;
    unsigned short* WqPk   = WoutPk + (size_t)NC * NC;

    k_pack<<<dim3(19), dim3(256), 0, stream>>>(Wv, Wout, Woff, Wattn, WvPk, WoutPk, WqPk);
    k_vproj<<<dim3(256), dim3(512), 0, stream>>>(value, WvPk, bv, vproj);
    k_offattn<<<dim3(NB * NQ / 32), dim3(256), 0, stream>>>(query, refp, WqPk, boff,
                                                            battn, locs, attnw);
    k_sample<<<dim3(NB * NQ / 16), dim3(256), 0, stream>>>(vproj, locs, attnw, WoutPk, bout, out);
}

// Round 5
// 74.131 us; speedup vs baseline: 3.7260x; 1.1159x over previous
//
#include <hip/hip_runtime.h>
#include <cstdint>

#define NB 4
#define NQ 8192
#define NC 256
#define IH 128
#define IW 128
#define NHW (IH * IW)
#define NHEADS 8
#define NP 4
#define NHD 32

typedef __bf16 bf16x8 __attribute__((ext_vector_type(8)));
typedef float f32x4 __attribute__((ext_vector_type(4)));

union FragCast { uint4 q; bf16x8 v; };

__device__ __forceinline__ unsigned int f2bf(float f) {
    unsigned int u = __float_as_uint(f);
    return (u + 0x7FFFu + ((u >> 16) & 1u)) >> 16;
}
__device__ __forceinline__ float bf2f(unsigned short s) {
    return __uint_as_float(((unsigned int)s) << 16);
}

// ---------------------------------------------------------------------------
// k_pack: repack weights (f32, row-major [K][cols]) into bf16 MFMA B-fragment
// order pk[(kt*COLS + col)*32 + j] = bf16(W[(kt*32+j)*COLS + col]).
// ---------------------------------------------------------------------------
__global__ __launch_bounds__(256) void k_pack(
    const float* __restrict__ Wv, const float* __restrict__ Wout,
    const float* __restrict__ Woff, const float* __restrict__ Wattn,
    unsigned short* __restrict__ pkv, unsigned short* __restrict__ pko,
    unsigned short* __restrict__ pkq)
{
    const int tid = blockIdx.x * 256 + threadIdx.x;   // 0..4863
    if (tid < 4096) {
        const float* src = (tid & 2048) ? Wout : Wv;
        unsigned short* dst = (tid & 2048) ? pko : pkv;
        const int rem = tid & 2047;
        const int kt = rem >> 8, col = rem & 255;
        unsigned short* d = dst + (size_t)(kt * 256 + col) * 32;
        const float* s = src + (size_t)kt * 32 * 256 + col;
#pragma unroll
        for (int j = 0; j < 32; ++j)
            d[j] = (unsigned short)f2bf(s[(size_t)j * 256]);
    } else {
        const int rem = tid - 4096;       // 0..767
        const int kt = rem / 96, col = rem % 96;
        unsigned short* d = pkq + (size_t)(kt * 96 + col) * 32;
        const float* s; int stride;
        if (col < 64) { s = Woff + col; stride = 64; }
        else          { s = Wattn + (col - 64); stride = 32; }
        s += (size_t)kt * 32 * stride;
#pragma unroll
        for (int j = 0; j < 32; ++j)
            d[j] = (unsigned short)f2bf(s[(size_t)j * stride]);
    }
}

// ---------------------------------------------------------------------------
// k_vproj: unchanged from round 4 (B fragments in registers, dbuf LDS).
// ---------------------------------------------------------------------------
#define VP_TPB 4
__global__ __launch_bounds__(512) void k_vproj(
    const float* __restrict__ value, const unsigned short* __restrict__ Bpk,
    const float* __restrict__ bv, unsigned short* __restrict__ vproj)
{
    const int t = threadIdx.x;
    const int l = t & 63, w = t >> 6;
    const int mh = w & 1, cg = w >> 1;

    __shared__ unsigned short A[2][64 * 256];

    uint4 bq[8][4];
#pragma unroll
    for (int kt = 0; kt < 8; ++kt)
#pragma unroll
        for (int i = 0; i < 4; ++i)
            bq[kt][i] = *reinterpret_cast<const uint4*>(
                Bpk + (size_t)kt * 8192 + (size_t)(cg * 4 + i) * 512 +
                (l & 15) * 32 + (l >> 4) * 8);

    float bb[4];
#pragma unroll
    for (int i = 0; i < 4; ++i) bb[i] = bv[cg * 64 + i * 16 + (l & 15)];

    const size_t tile0 = (size_t)blockIdx.x * VP_TPB;

    float4 st[8];
#pragma unroll
    for (int i = 0; i < 8; ++i) {
        const int chunk = i * 512 + t;
        const int row = chunk >> 6, k0 = (chunk & 63) * 4;
        st[i] = *reinterpret_cast<const float4*>(&value[(tile0 * 64 + row) * NC + k0]);
    }
#pragma unroll
    for (int i = 0; i < 8; ++i) {
        const int chunk = i * 512 + t;
        const int row = chunk >> 6, k0 = (chunk & 63) * 4;
        unsigned int byte = (unsigned int)(row * 512 + k0 * 2) ^ (unsigned int)((row & 7) << 4);
        *reinterpret_cast<uint2*>(reinterpret_cast<char*>(A[0]) + byte) =
            make_uint2(f2bf(st[i].x) | (f2bf(st[i].y) << 16),
                       f2bf(st[i].z) | (f2bf(st[i].w) << 16));
    }
    __syncthreads();

    for (int tt = 0; tt < VP_TPB; ++tt) {
        const int cur = tt & 1;
        if (tt + 1 < VP_TPB) {
#pragma unroll
            for (int i = 0; i < 8; ++i) {
                const int chunk = i * 512 + t;
                const int row = chunk >> 6, k0 = (chunk & 63) * 4;
                st[i] = *reinterpret_cast<const float4*>(
                    &value[((tile0 + tt + 1) * 64 + row) * NC + k0]);
            }
        }

        f32x4 acc[2][4];
#pragma unroll
        for (int m = 0; m < 2; ++m)
#pragma unroll
            for (int i = 0; i < 4; ++i) acc[m][i] = (f32x4)(bb[i]);

#pragma unroll
        for (int kt = 0; kt < 8; ++kt) {
#pragma unroll
            for (int m = 0; m < 2; ++m) {
                const int arow = mh * 32 + m * 16 + (l & 15);
                unsigned int abyte = (unsigned int)(arow * 512 + (kt * 32 + (l >> 4) * 8) * 2)
                                   ^ (unsigned int)((arow & 7) << 4);
                FragCast af;
                af.q = *reinterpret_cast<const uint4*>(reinterpret_cast<const char*>(A[cur]) + abyte);
#pragma unroll
                for (int i = 0; i < 4; ++i) {
                    FragCast bfc; bfc.q = bq[kt][i];
                    acc[m][i] = __builtin_amdgcn_mfma_f32_16x16x32_bf16(af.v, bfc.v, acc[m][i], 0, 0, 0);
                }
            }
        }

        const size_t rowbase = (tile0 + tt) * 64;
#pragma unroll
        for (int m = 0; m < 2; ++m)
#pragma unroll
            for (int i = 0; i < 4; ++i) {
                const int col = cg * 64 + i * 16 + (l & 15);
#pragma unroll
                for (int j = 0; j < 4; ++j) {
                    const size_t row = rowbase + mh * 32 + m * 16 + (l >> 4) * 4 + j;
                    vproj[row * NC + col] = (unsigned short)f2bf(acc[m][i][j]);
                }
            }

        if (tt + 1 < VP_TPB) {
#pragma unroll
            for (int i = 0; i < 8; ++i) {
                const int chunk = i * 512 + t;
                const int row = chunk >> 6, k0 = (chunk & 63) * 4;
                unsigned int byte = (unsigned int)(row * 512 + k0 * 2) ^ (unsigned int)((row & 7) << 4);
                *reinterpret_cast<uint2*>(reinterpret_cast<char*>(A[cur ^ 1]) + byte) =
                    make_uint2(f2bf(st[i].x) | (f2bf(st[i].y) << 16),
                               f2bf(st[i].z) | (f2bf(st[i].w) << 16));
            }
            __syncthreads();
        }
    }
}

// ---------------------------------------------------------------------------
// k_fused: per 16 queries -- (1) offsets/attn MFMA + softmax -> LDS,
// (2) bilinear gather with sched_barrier-pinned 16-deep load batches,
// (3) out-projection MFMA. 256 thr / 4 waves.
// ---------------------------------------------------------------------------
__global__ __launch_bounds__(256) void k_fused(
    const float* __restrict__ query, const float* __restrict__ refp,
    const unsigned short* __restrict__ Bq, const float* __restrict__ boff,
    const float* __restrict__ battn, const unsigned short* __restrict__ vproj,
    const unsigned short* __restrict__ Bo, const float* __restrict__ bout,
    float* __restrict__ out)
{
    const int t = threadIdx.x;
    const int l = t & 63, w = t >> 6;
    const size_t q0 = (size_t)blockIdx.x * 16;
    const int b = (int)(q0 / NQ);

    __shared__ unsigned short A[16 * 256];   // 8 KB: query bf16 (ph1), agg (ph2/3)
    __shared__ float locs_s[16][64];         // 4 KB
    __shared__ float attn_s[16][32];         // 2 KB
    __shared__ float refs[16][2];

    // stage query -> swizzled bf16 LDS
#pragma unroll
    for (int i = 0; i < 4; ++i) {
        const int chunk = i * 256 + t;
        const int row = chunk >> 6, k0 = (chunk & 63) * 4;
        const float4 v4 = *reinterpret_cast<const float4*>(&query[(q0 + row) * NC + k0]);
        unsigned int byte = (unsigned int)(row * 512 + k0 * 2) ^ (unsigned int)((row & 7) << 4);
        *reinterpret_cast<uint2*>(reinterpret_cast<char*>(A) + byte) =
            make_uint2(f2bf(v4.x) | (f2bf(v4.y) << 16),
                       f2bf(v4.z) | (f2bf(v4.w) << 16));
    }
    if (t < 32) reinterpret_cast<float*>(refs)[t] = refp[q0 * 2 + t];
    __syncthreads();

    // ---- phase 1: [offsets|attn] = q @ Wq, epilogue into locs_s/attn_s ----
    {
        const int arow = l & 15, achunk = l >> 4;
#pragma unroll
        for (int pass = 0; pass < 2; ++pass) {
            if (pass == 1 && w >= 2) break;
            const int ct = pass == 0 ? w : 4 + w;
            f32x4 acc = (f32x4)(0.f);
#pragma unroll
            for (int kt = 0; kt < 8; ++kt) {
                unsigned int abyte = (unsigned int)(arow * 512 + (kt * 32 + achunk * 8) * 2)
                                   ^ (unsigned int)((arow & 7) << 4);
                FragCast af;
                af.q = *reinterpret_cast<const uint4*>(reinterpret_cast<const char*>(A) + abyte);
                FragCast bfc;
                bfc.q = *reinterpret_cast<const uint4*>(
                    Bq + (size_t)kt * 3072 + (size_t)(ct * 16 + arow) * 32 + achunk * 8);
                acc = __builtin_amdgcn_mfma_f32_16x16x32_bf16(af.v, bfc.v, acc, 0, 0, 0);
            }
            const int col = ct * 16 + arow;
            if (col < 64) {
                const float bias = boff[col];
                const int xy = col & 1;
#pragma unroll
                for (int j = 0; j < 4; ++j) {
                    const int row = achunk * 4 + j;
                    float off = acc[j] + bias;
                    float loc = refs[row][xy] + off * (0.1f / 128.0f);
                    locs_s[row][col] = fminf(fmaxf(loc, 0.f), 1.f);
                }
            } else {
                const int lc = col - 64;
                const float bias = battn[lc];
#pragma unroll
                for (int j = 0; j < 4; ++j) {
                    const int row = achunk * 4 + j;
                    float v = acc[j] + bias;
                    float m = fmaxf(v, __shfl_xor(v, 1));
                    m = fmaxf(m, __shfl_xor(m, 2));
                    float e = __expf(v - m);
                    float s = e + __shfl_xor(e, 1);
                    s = s + __shfl_xor(s, 2);
                    attn_s[row][lc] = e / s;
                }
            }
        }
    }
    __syncthreads();

    // ---- phase 2: bilinear gather, 16 loads pinned in flight ----
    {
        const int rhalf = l >> 5, h = (l >> 2) & 7, c = l & 3;
        const unsigned short* __restrict__ vb =
            vproj + (size_t)b * NHW * NC + h * NHD + c * 8;

#pragma unroll
        for (int it = 0; it < 2; ++it) {
            const int r = w * 4 + it * 2 + rhalf;
            float wts[16];
            uint4 vals[16];
#pragma unroll
            for (int p = 0; p < 4; ++p) {
                const float lx = locs_s[r][h * 8 + p * 2 + 0];
                const float ly = locs_s[r][h * 8 + p * 2 + 1];
                const float aw = attn_s[r][h * 4 + p];
                const float x = lx * (float)IW - 0.5f;
                const float y = ly * (float)IH - 0.5f;
                const float x0f = floorf(x), y0f = floorf(y);
                const float wx = x - x0f, wy = y - y0f;
                const int ix0 = (int)x0f, iy0 = (int)y0f;
                const int ix1 = ix0 + 1, iy1 = iy0 + 1;
                const int cx0 = max(ix0, 0), cy0 = max(iy0, 0);
                const int cx1 = min(ix1, IW - 1), cy1 = min(iy1, IH - 1);
                const float vx0 = (ix0 >= 0) ? 1.f : 0.f;
                const float vy0 = (iy0 >= 0) ? 1.f : 0.f;
                const float vx1 = (ix1 < IW) ? 1.f : 0.f;
                const float vy1 = (iy1 < IH) ? 1.f : 0.f;
                wts[p * 4 + 0] = aw * ((1.f - wx) * (1.f - wy) * vx0 * vy0);
                wts[p * 4 + 1] = aw * (wx * (1.f - wy) * vx1 * vy0);
                wts[p * 4 + 2] = aw * ((1.f - wx) * wy * vx0 * vy1);
                wts[p * 4 + 3] = aw * (wx * wy * vx1 * vy1);
                vals[p * 4 + 0] = *reinterpret_cast<const uint4*>(vb + (size_t)(cy0 * IW + cx0) * NC);
                vals[p * 4 + 1] = *reinterpret_cast<const uint4*>(vb + (size_t)(cy0 * IW + cx1) * NC);
                vals[p * 4 + 2] = *reinterpret_cast<const uint4*>(vb + (size_t)(cy1 * IW + cx0) * NC);
                vals[p * 4 + 3] = *reinterpret_cast<const uint4*>(vb + (size_t)(cy1 * IW + cx1) * NC);
            }
            // pin: all 16 loads issued before any consumption (forces MLP)
            __builtin_amdgcn_sched_barrier(0);
            float acc[8];
#pragma unroll
            for (int e = 0; e < 8; ++e) acc[e] = 0.f;
#pragma unroll
            for (int j = 0; j < 16; ++j) {
                const unsigned short* u = reinterpret_cast<const unsigned short*>(&vals[j]);
                const float wj = wts[j];
#pragma unroll
                for (int e = 0; e < 8; ++e) acc[e] = fmaf(wj, bf2f(u[e]), acc[e]);
            }
            uint4 pk;
            pk.x = f2bf(acc[0]) | (f2bf(acc[1]) << 16);
            pk.y = f2bf(acc[2]) | (f2bf(acc[3]) << 16);
            pk.z = f2bf(acc[4]) | (f2bf(acc[5]) << 16);
            pk.w = f2bf(acc[6]) | (f2bf(acc[7]) << 16);
            unsigned int byte = (unsigned int)(r * 512 + (h * NHD + c * 8) * 2)
                              ^ (unsigned int)((r & 7) << 4);
            *reinterpret_cast<uint4*>(reinterpret_cast<char*>(A) + byte) = pk;
        }
    }
    __syncthreads();

    // ---- phase 3: out = agg @ Wout + bout ----
    {
        const int arow = l & 15, achunk = l >> 4;
        f32x4 acc2[4];
#pragma unroll
        for (int i = 0; i < 4; ++i) acc2[i] = (f32x4)(0.f);

#pragma unroll
        for (int kt = 0; kt < 8; ++kt) {
            unsigned int abyte = (unsigned int)(arow * 512 + (kt * 32 + achunk * 8) * 2)
                               ^ (unsigned int)((arow & 7) << 4);
            FragCast af;
            af.q = *reinterpret_cast<const uint4*>(reinterpret_cast<const char*>(A) + abyte);
            const unsigned short* bbase = Bo + (size_t)kt * 8192 + arow * 32 + achunk * 8;
#pragma unroll
            for (int i = 0; i < 4; ++i) {
                const int ct = w * 4 + i;
                FragCast bfc;
                bfc.q = *reinterpret_cast<const uint4*>(bbase + (size_t)ct * 512);
                acc2[i] = __builtin_amdgcn_mfma_f32_16x16x32_bf16(af.v, bfc.v, acc2[i], 0, 0, 0);
            }
        }

#pragma unroll
        for (int i = 0; i < 4; ++i) {
            const int col = (w * 4 + i) * 16 + arow;
            const float bbv = bout[col];
#pragma unroll
            for (int j = 0; j < 4; ++j) {
                const size_t row = q0 + achunk * 4 + j;
                out[row * NC + col] = acc2[i][j] + bbv;
            }
        }
    }
}

extern "C" void kernel_launch(void* const* d_in, const int* in_sizes, int n_in,
                              void* d_out, int out_size, void* d_ws, size_t ws_size,
                              hipStream_t stream) {
    const float* query = (const float*)d_in[0];
    const float* refp  = (const float*)d_in[1];
    const float* value = (const float*)d_in[2];
    const float* Woff  = (const float*)d_in[3];
    const float* boff  = (const float*)d_in[4];
    const float* Wattn = (const float*)d_in[5];
    const float* battn = (const float*)d_in[6];
    const float* Wv    = (const float*)d_in[7];
    const float* bv    = (const float*)d_in[8];
    const float* Wout  = (const float*)d_in[9];
    const float* bout  = (const float*)d_in[10];
    float* out = (float*)d_out;

    unsigned short* vproj  = (unsigned short*)d_ws;                  // 32 MB
    unsigned short* WvPk   = vproj + (size_t)NB * NHW * NC;          // 128 KB
    unsigned short* WoutPk = WvPk + (size_t)NC * NC;                 // 128 KB
    unsigned short* WqPk   = WoutPk + (size_t)NC * NC;               //  48 KB

    k_pack<<<dim3(19), dim3(256), 0, stream>>>(Wv, Wout, Woff, Wattn, WvPk, WoutPk, WqPk);
    k_vproj<<<dim3(256), dim3(512), 0, stream>>>(value, WvPk, bv, vproj);
    k_fused<<<dim3(NB * NQ / 16), dim3(256), 0, stream>>>(query, refp, WqPk, boff, battn,
                                                          vproj, WoutPk, bout, out);
}

// Round 6
// 72.587 us; speedup vs baseline: 3.8053x; 1.0213x over previous
//
#include <hip/hip_runtime.h>
#include <cstdint>

#define NB 4
#define NQ 8192
#define NC 256
#define IH 128
#define IW 128
#define NHW (IH * IW)
#define NHEADS 8
#define NP 4
#define NHD 32

typedef __bf16 bf16x8 __attribute__((ext_vector_type(8)));
typedef float f32x4 __attribute__((ext_vector_type(4)));

union FragCast { uint4 q; bf16x8 v; };

__device__ __forceinline__ unsigned int f2bf(float f) {
    unsigned int u = __float_as_uint(f);
    return (u + 0x7FFFu + ((u >> 16) & 1u)) >> 16;
}
__device__ __forceinline__ float bf2f(unsigned short s) {
    return __uint_as_float(((unsigned int)s) << 16);
}

// ---------------------------------------------------------------------------
// k_pack: repack weights (f32, row-major [K][cols]) into bf16 MFMA B-fragment
// order pk[(kt*COLS + col)*32 + j] = bf16(W[(kt*32+j)*COLS + col]).
// ---------------------------------------------------------------------------
__global__ __launch_bounds__(256) void k_pack(
    const float* __restrict__ Wv, const float* __restrict__ Wout,
    const float* __restrict__ Woff, const float* __restrict__ Wattn,
    unsigned short* __restrict__ pkv, unsigned short* __restrict__ pko,
    unsigned short* __restrict__ pkq)
{
    const int tid = blockIdx.x * 256 + threadIdx.x;   // 0..4863
    if (tid < 4096) {
        const float* src = (tid & 2048) ? Wout : Wv;
        unsigned short* dst = (tid & 2048) ? pko : pkv;
        const int rem = tid & 2047;
        const int kt = rem >> 8, col = rem & 255;
        unsigned short* d = dst + (size_t)(kt * 256 + col) * 32;
        const float* s = src + (size_t)kt * 32 * 256 + col;
#pragma unroll
        for (int j = 0; j < 32; ++j)
            d[j] = (unsigned short)f2bf(s[(size_t)j * 256]);
    } else {
        const int rem = tid - 4096;       // 0..767
        const int kt = rem / 96, col = rem % 96;
        unsigned short* d = pkq + (size_t)(kt * 96 + col) * 32;
        const float* s; int stride;
        if (col < 64) { s = Woff + col; stride = 64; }
        else          { s = Wattn + (col - 64); stride = 32; }
        s += (size_t)kt * 32 * stride;
#pragma unroll
        for (int j = 0; j < 32; ++j)
            d[j] = (unsigned short)f2bf(s[(size_t)j * stride]);
    }
}

// ---------------------------------------------------------------------------
// k_vproj: unchanged (B fragments in registers, dbuf LDS).
// ---------------------------------------------------------------------------
#define VP_TPB 4
__global__ __launch_bounds__(512) void k_vproj(
    const float* __restrict__ value, const unsigned short* __restrict__ Bpk,
    const float* __restrict__ bv, unsigned short* __restrict__ vproj)
{
    const int t = threadIdx.x;
    const int l = t & 63, w = t >> 6;
    const int mh = w & 1, cg = w >> 1;

    __shared__ unsigned short A[2][64 * 256];

    uint4 bq[8][4];
#pragma unroll
    for (int kt = 0; kt < 8; ++kt)
#pragma unroll
        for (int i = 0; i < 4; ++i)
            bq[kt][i] = *reinterpret_cast<const uint4*>(
                Bpk + (size_t)kt * 8192 + (size_t)(cg * 4 + i) * 512 +
                (l & 15) * 32 + (l >> 4) * 8);

    float bb[4];
#pragma unroll
    for (int i = 0; i < 4; ++i) bb[i] = bv[cg * 64 + i * 16 + (l & 15)];

    const size_t tile0 = (size_t)blockIdx.x * VP_TPB;

    float4 st[8];
#pragma unroll
    for (int i = 0; i < 8; ++i) {
        const int chunk = i * 512 + t;
        const int row = chunk >> 6, k0 = (chunk & 63) * 4;
        st[i] = *reinterpret_cast<const float4*>(&value[(tile0 * 64 + row) * NC + k0]);
    }
#pragma unroll
    for (int i = 0; i < 8; ++i) {
        const int chunk = i * 512 + t;
        const int row = chunk >> 6, k0 = (chunk & 63) * 4;
        unsigned int byte = (unsigned int)(row * 512 + k0 * 2) ^ (unsigned int)((row & 7) << 4);
        *reinterpret_cast<uint2*>(reinterpret_cast<char*>(A[0]) + byte) =
            make_uint2(f2bf(st[i].x) | (f2bf(st[i].y) << 16),
                       f2bf(st[i].z) | (f2bf(st[i].w) << 16));
    }
    __syncthreads();

    for (int tt = 0; tt < VP_TPB; ++tt) {
        const int cur = tt & 1;
        if (tt + 1 < VP_TPB) {
#pragma unroll
            for (int i = 0; i < 8; ++i) {
                const int chunk = i * 512 + t;
                const int row = chunk >> 6, k0 = (chunk & 63) * 4;
                st[i] = *reinterpret_cast<const float4*>(
                    &value[((tile0 + tt + 1) * 64 + row) * NC + k0]);
            }
        }

        f32x4 acc[2][4];
#pragma unroll
        for (int m = 0; m < 2; ++m)
#pragma unroll
            for (int i = 0; i < 4; ++i) acc[m][i] = (f32x4)(bb[i]);

#pragma unroll
        for (int kt = 0; kt < 8; ++kt) {
#pragma unroll
            for (int m = 0; m < 2; ++m) {
                const int arow = mh * 32 + m * 16 + (l & 15);
                unsigned int abyte = (unsigned int)(arow * 512 + (kt * 32 + (l >> 4) * 8) * 2)
                                   ^ (unsigned int)((arow & 7) << 4);
                FragCast af;
                af.q = *reinterpret_cast<const uint4*>(reinterpret_cast<const char*>(A[cur]) + abyte);
#pragma unroll
                for (int i = 0; i < 4; ++i) {
                    FragCast bfc; bfc.q = bq[kt][i];
                    acc[m][i] = __builtin_amdgcn_mfma_f32_16x16x32_bf16(af.v, bfc.v, acc[m][i], 0, 0, 0);
                }
            }
        }

        const size_t rowbase = (tile0 + tt) * 64;
#pragma unroll
        for (int m = 0; m < 2; ++m)
#pragma unroll
            for (int i = 0; i < 4; ++i) {
                const int col = cg * 64 + i * 16 + (l & 15);
#pragma unroll
                for (int j = 0; j < 4; ++j) {
                    const size_t row = rowbase + mh * 32 + m * 16 + (l >> 4) * 4 + j;
                    vproj[row * NC + col] = (unsigned short)f2bf(acc[m][i][j]);
                }
            }

        if (tt + 1 < VP_TPB) {
#pragma unroll
            for (int i = 0; i < 8; ++i) {
                const int chunk = i * 512 + t;
                const int row = chunk >> 6, k0 = (chunk & 63) * 4;
                unsigned int byte = (unsigned int)(row * 512 + k0 * 2) ^ (unsigned int)((row & 7) << 4);
                *reinterpret_cast<uint2*>(reinterpret_cast<char*>(A[cur ^ 1]) + byte) =
                    make_uint2(f2bf(st[i].x) | (f2bf(st[i].y) << 16),
                               f2bf(st[i].z) | (f2bf(st[i].w) << 16));
            }
            __syncthreads();
        }
    }
}

// ---------------------------------------------------------------------------
// k_fused: (1) offsets/attn MFMA + softmax -> LDS, (2) bilinear gather with
// 32-deep pinned load batches (addresses hoisted, 32-bit offsets off uniform
// base), (3) out-projection MFMA. 256 thr / 4 waves, 16 queries/block.
// ---------------------------------------------------------------------------
__global__ __launch_bounds__(256) void k_fused(
    const float* __restrict__ query, const float* __restrict__ refp,
    const unsigned short* __restrict__ Bq, const float* __restrict__ boff,
    const float* __restrict__ battn, const unsigned short* __restrict__ vproj,
    const unsigned short* __restrict__ Bo, const float* __restrict__ bout,
    float* __restrict__ out)
{
    const int t = threadIdx.x;
    const int l = t & 63, w = t >> 6;
    const size_t q0 = (size_t)blockIdx.x * 16;
    const int b = (int)(q0 / NQ);

    __shared__ unsigned short A[16 * 256];   // 8 KB: query bf16 (ph1), agg (ph2/3)
    __shared__ float locs_s[16][64];         // 4 KB
    __shared__ float attn_s[16][32];         // 2 KB
    __shared__ float refs[16][2];

    // stage query -> swizzled bf16 LDS
#pragma unroll
    for (int i = 0; i < 4; ++i) {
        const int chunk = i * 256 + t;
        const int row = chunk >> 6, k0 = (chunk & 63) * 4;
        const float4 v4 = *reinterpret_cast<const float4*>(&query[(q0 + row) * NC + k0]);
        unsigned int byte = (unsigned int)(row * 512 + k0 * 2) ^ (unsigned int)((row & 7) << 4);
        *reinterpret_cast<uint2*>(reinterpret_cast<char*>(A) + byte) =
            make_uint2(f2bf(v4.x) | (f2bf(v4.y) << 16),
                       f2bf(v4.z) | (f2bf(v4.w) << 16));
    }
    if (t < 32) reinterpret_cast<float*>(refs)[t] = refp[q0 * 2 + t];
    __syncthreads();

    // ---- phase 1: [offsets|attn] = q @ Wq, epilogue into locs_s/attn_s ----
    {
        const int arow = l & 15, achunk = l >> 4;
#pragma unroll
        for (int pass = 0; pass < 2; ++pass) {
            if (pass == 1 && w >= 2) break;
            const int ct = pass == 0 ? w : 4 + w;
            f32x4 acc = (f32x4)(0.f);
#pragma unroll
            for (int kt = 0; kt < 8; ++kt) {
                unsigned int abyte = (unsigned int)(arow * 512 + (kt * 32 + achunk * 8) * 2)
                                   ^ (unsigned int)((arow & 7) << 4);
                FragCast af;
                af.q = *reinterpret_cast<const uint4*>(reinterpret_cast<const char*>(A) + abyte);
                FragCast bfc;
                bfc.q = *reinterpret_cast<const uint4*>(
                    Bq + (size_t)kt * 3072 + (size_t)(ct * 16 + arow) * 32 + achunk * 8);
                acc = __builtin_amdgcn_mfma_f32_16x16x32_bf16(af.v, bfc.v, acc, 0, 0, 0);
            }
            const int col = ct * 16 + arow;
            if (col < 64) {
                const float bias = boff[col];
                const int xy = col & 1;
#pragma unroll
                for (int j = 0; j < 4; ++j) {
                    const int row = achunk * 4 + j;
                    float off = acc[j] + bias;
                    float loc = refs[row][xy] + off * (0.1f / 128.0f);
                    locs_s[row][col] = fminf(fmaxf(loc, 0.f), 1.f);
                }
            } else {
                const int lc = col - 64;
                const float bias = battn[lc];
#pragma unroll
                for (int j = 0; j < 4; ++j) {
                    const int row = achunk * 4 + j;
                    float v = acc[j] + bias;
                    float m = fmaxf(v, __shfl_xor(v, 1));
                    m = fmaxf(m, __shfl_xor(m, 2));
                    float e = __expf(v - m);
                    float s = e + __shfl_xor(e, 1);
                    s = s + __shfl_xor(s, 2);
                    attn_s[row][lc] = e / s;
                }
            }
        }
    }
    __syncthreads();

    // ---- phase 2: bilinear gather, 32 loads in flight per lane ----
    {
        const int rhalf = l >> 5, h = (l >> 2) & 7, c = l & 3;
        // wave-uniform 64-bit base; per-lane constant folded into offsets
        const char* __restrict__ vbase =
            reinterpret_cast<const char*>(vproj + (size_t)b * NHW * NC);
        const unsigned int laneoff = (unsigned int)((h * NHD + c * 8) * 2);

        float wts[2][16];
        unsigned int offs[2][16];
#pragma unroll
        for (int it = 0; it < 2; ++it) {
            const int r = w * 4 + it * 2 + rhalf;
#pragma unroll
            for (int p = 0; p < 4; ++p) {
                const float lx = locs_s[r][h * 8 + p * 2 + 0];
                const float ly = locs_s[r][h * 8 + p * 2 + 1];
                const float aw = attn_s[r][h * 4 + p];
                const float x = lx * (float)IW - 0.5f;
                const float y = ly * (float)IH - 0.5f;
                const float x0f = floorf(x), y0f = floorf(y);
                const float wx = x - x0f, wy = y - y0f;
                const int ix0 = (int)x0f, iy0 = (int)y0f;
                const int ix1 = ix0 + 1, iy1 = iy0 + 1;
                const int cx0 = max(ix0, 0), cy0 = max(iy0, 0);
                const int cx1 = min(ix1, IW - 1), cy1 = min(iy1, IH - 1);
                const float vx0 = (ix0 >= 0) ? 1.f : 0.f;
                const float vy0 = (iy0 >= 0) ? 1.f : 0.f;
                const float vx1 = (ix1 < IW) ? 1.f : 0.f;
                const float vy1 = (iy1 < IH) ? 1.f : 0.f;
                wts[it][p * 4 + 0] = aw * ((1.f - wx) * (1.f - wy) * vx0 * vy0);
                wts[it][p * 4 + 1] = aw * (wx * (1.f - wy) * vx1 * vy0);
                wts[it][p * 4 + 2] = aw * ((1.f - wx) * wy * vx0 * vy1);
                wts[it][p * 4 + 3] = aw * (wx * wy * vx1 * vy1);
                offs[it][p * 4 + 0] = (unsigned int)(cy0 * IW + cx0) * 512u + laneoff;
                offs[it][p * 4 + 1] = (unsigned int)(cy0 * IW + cx1) * 512u + laneoff;
                offs[it][p * 4 + 2] = (unsigned int)(cy1 * IW + cx0) * 512u + laneoff;
                offs[it][p * 4 + 3] = (unsigned int)(cy1 * IW + cx1) * 512u + laneoff;
            }
        }

        uint4 vals0[16], vals1[16];
#pragma unroll
        for (int j = 0; j < 16; ++j)
            vals0[j] = *reinterpret_cast<const uint4*>(vbase + offs[0][j]);
        __builtin_amdgcn_sched_barrier(0);
#pragma unroll
        for (int j = 0; j < 16; ++j)
            vals1[j] = *reinterpret_cast<const uint4*>(vbase + offs[1][j]);
        __builtin_amdgcn_sched_barrier(0);

#pragma unroll
        for (int it = 0; it < 2; ++it) {
            const int r = w * 4 + it * 2 + rhalf;
            float acc[8];
#pragma unroll
            for (int e = 0; e < 8; ++e) acc[e] = 0.f;
#pragma unroll
            for (int j = 0; j < 16; ++j) {
                const uint4 vq = it == 0 ? vals0[j] : vals1[j];
                const unsigned short* u = reinterpret_cast<const unsigned short*>(&vq);
                const float wj = wts[it][j];
#pragma unroll
                for (int e = 0; e < 8; ++e) acc[e] = fmaf(wj, bf2f(u[e]), acc[e]);
            }
            uint4 pk;
            pk.x = f2bf(acc[0]) | (f2bf(acc[1]) << 16);
            pk.y = f2bf(acc[2]) | (f2bf(acc[3]) << 16);
            pk.z = f2bf(acc[4]) | (f2bf(acc[5]) << 16);
            pk.w = f2bf(acc[6]) | (f2bf(acc[7]) << 16);
            unsigned int byte = (unsigned int)(r * 512 + (h * NHD + c * 8) * 2)
                              ^ (unsigned int)((r & 7) << 4);
            *reinterpret_cast<uint4*>(reinterpret_cast<char*>(A) + byte) = pk;
        }
    }
    __syncthreads();

    // ---- phase 3: out = agg @ Wout + bout ----
    {
        const int arow = l & 15, achunk = l >> 4;
        f32x4 acc2[4];
#pragma unroll
        for (int i = 0; i < 4; ++i) acc2[i] = (f32x4)(0.f);

#pragma unroll
        for (int kt = 0; kt < 8; ++kt) {
            unsigned int abyte = (unsigned int)(arow * 512 + (kt * 32 + achunk * 8) * 2)
                               ^ (unsigned int)((arow & 7) << 4);
            FragCast af;
            af.q = *reinterpret_cast<const uint4*>(reinterpret_cast<const char*>(A) + abyte);
            const unsigned short* bbase = Bo + (size_t)kt * 8192 + arow * 32 + achunk * 8;
#pragma unroll
            for (int i = 0; i < 4; ++i) {
                const int ct = w * 4 + i;
                FragCast bfc;
                bfc.q = *reinterpret_cast<const uint4*>(bbase + (size_t)ct * 512);
                acc2[i] = __builtin_amdgcn_mfma_f32_16x16x32_bf16(af.v, bfc.v, acc2[i], 0, 0, 0);
            }
        }

#pragma unroll
        for (int i = 0; i < 4; ++i) {
            const int col = (w * 4 + i) * 16 + arow;
            const float bbv = bout[col];
#pragma unroll
            for (int j = 0; j < 4; ++j) {
                const size_t row = q0 + achunk * 4 + j;
                out[row * NC + col] = acc2[i][j] + bbv;
            }
        }
    }
}

extern "C" void kernel_launch(void* const* d_in, const int* in_sizes, int n_in,
                              void* d_out, int out_size, void* d_ws, size_t ws_size,
                              hipStream_t stream) {
    const float* query = (const float*)d_in[0];
    const float* refp  = (const float*)d_in[1];
    const float* value = (const float*)d_in[2];
    const float* Woff  = (const float*)d_in[3];
    const float* boff  = (const float*)d_in[4];
    const float* Wattn = (const float*)d_in[5];
    const float* battn = (const float*)d_in[6];
    const float* Wv    = (const float*)d_in[7];
    const float* bv    = (const float*)d_in[8];
    const float* Wout  = (const float*)d_in[9];
    const float* bout  = (const float*)d_in[10];
    float* out = (float*)d_out;

    unsigned short* vproj  = (unsigned short*)d_ws;                  // 32 MB
    unsigned short* WvPk   = vproj + (size_t)NB * NHW * NC;          // 128 KB
    unsigned short* WoutPk = WvPk + (size_t)NC * NC;                 // 128 KB
    unsigned short* WqPk   = WoutPk + (size_t)NC * NC;               //  48 KB

    k_pack<<<dim3(19), dim3(256), 0, stream>>>(Wv, Wout, Woff, Wattn, WvPk, WoutPk, WqPk);
    k_vproj<<<dim3(256), dim3(512), 0, stream>>>(value, WvPk, bv, vproj);
    k_fused<<<dim3(NB * NQ / 16), dim3(256), 0, stream>>>(query, refp, WqPk, boff, battn,
                                                          vproj, WoutPk, bout, out);
}